// Round 11
// baseline (189.228 us; speedup 1.0000x reference)
//
#include <hip/hip_runtime.h>
#include <math.h>

#define NG 800000        // = 12500 chunks of 64 rows
#define NCH 12500
#define GRID 256
#define BLK 512
#define WPB 8
#define NSTATIC 2048     // GRID * WPB

typedef __attribute__((ext_vector_type(8))) short short8;
typedef __attribute__((ext_vector_type(4))) float f32x4;

// ---- shared LDS layout (bytes) ----
#define W2T_OFF 0        // 16384  [c=128][k=64] bf16 swz
#define W3T_OFF 16384    // 24576  [c=96][k=128] bf16 swz
#define WIT_OFF 40960    //  6144  [c=96][k=32]  bf16 swz
#define B2_OFF  47104    //   512  f32[128]
#define BC_OFF  47616    //   384  f32[96]
#define WV_OFF  48128    // 8 waves x 11520
// per-wave region (11520 B):
#define X_OFF 0          //  6656  gp tile -> oA staging -> (H1S,H2S) -> oI staging
#define H1S   0          //  alias: 2048  [16][64]  bf16 swz strip
#define H2S   2048       //  alias: 4096  [16][128] bf16 swz strip
#define ANB   6656       //  4096  [64][32] bf16 swz
#define DFP   10752      //   512  float2[64]
#define SMK   11264      //   256  float[64]
#define WV_SZ 11520
#define LDS_TOT (WV_OFF + WPB * WV_SZ)   // 140288

__device__ __forceinline__ float sis(float t) {
    t = fminf(fmaxf(t, 0.01f), 0.99f);
    return logf(t / (1.0f - t));
}
__device__ __forceinline__ unsigned short f2bf(float f) {
    unsigned int u = __float_as_uint(f);
    return (unsigned short)((u + 0x7FFFu + ((u >> 16) & 1u)) >> 16);
}
__device__ __forceinline__ unsigned int cvtpk(float a, float b) {
    unsigned int r;
    asm("v_cvt_pk_bf16_f32 %0, %1, %2" : "=v"(r) : "v"(a), "v"(b));
    return r;
}

__global__ __launch_bounds__(BLK, 2) void k_main(
    const float* __restrict__ gp,
    const float* __restrict__ zbuf,
    const float* __restrict__ w2c,
    const float* __restrict__ ck,
    const float* __restrict__ vo,
    const float* __restrict__ ss,
    const float* __restrict__ cvr,
    const float* __restrict__ W1, const float* __restrict__ b1,
    const float* __restrict__ W2, const float* __restrict__ b2,
    const float* __restrict__ W3, const float* __restrict__ b3,
    const float* __restrict__ Wi, const float* __restrict__ bi,
    float* __restrict__ oA, float* __restrict__ oT,
    float* __restrict__ oI, float* __restrict__ oP, float* __restrict__ oM,
    int* __restrict__ ctr, int usews)
{
    __shared__ __align__(16) char lds[LDS_TOT];
    float* sB2 = (float*)(lds + B2_OFF);
    float* sBC = (float*)(lds + BC_OFF);

    const int t   = threadIdx.x;
    const int wv  = t >> 6;
    const int l   = t & 63;
    const int la  = l & 15;
    const int lb  = l >> 4;
    const int sub = l & 3;
    char* wlds = lds + WV_OFF + wv * WV_SZ;
    float*  xf  = (float*)(wlds + X_OFF);
    float2* dfp = (float2*)(wlds + DFP);
    float*  smk = (float*)(wlds + SMK);

    // ---- build shared weight images (once per block) ----
    for (int idx = t; idx < 8192; idx += BLK) {            // W2T
        int k = idx >> 7, c = idx & 127;
        *(unsigned short*)(lds + W2T_OFF + c*128 + (((k>>3) ^ (c&7))<<4) + (k&7)*2)
            = f2bf(W2[idx]);
    }
    for (int idx = t; idx < 12288; idx += BLK) {           // W3T
        int k = idx / 96, c = idx - k*96;
        *(unsigned short*)(lds + W3T_OFF + c*256 + (((k>>3) ^ (c&15))<<4) + (k&7)*2)
            = f2bf(W3[idx]);
    }
    for (int idx = t; idx < 3072; idx += BLK) {            // WIT
        int c = idx >> 5, k = idx & 31;
        float val = (k < 23) ? Wi[k*96 + c] : 0.0f;
        *(unsigned short*)(lds + WIT_OFF + c*64 + (((k>>3) ^ (c&3))<<4) + (k&7)*2)
            = f2bf(val);
    }
    if (t < 128) sB2[t] = b2[t];
    if (t < 96)  sBC[t] = b3[t] + bi[t];

    // per-lane W1/b1 column block (cols sub*16..sub*16+15) in registers
    float4 w1a[4], w1b[4], b1r[4];
    #pragma unroll
    for (int gi = 0; gi < 4; ++gi) {
        w1a[gi] = *(const float4*)&W1[sub*16 + gi*4];
        w1b[gi] = *(const float4*)&W1[64 + sub*16 + gi*4];
        b1r[gi] = *(const float4*)&b1[sub*16 + gi*4];
    }

    // uniforms
    const float R00=w2c[0],R01=w2c[1],R02=w2c[2],T0=w2c[3];
    const float R10=w2c[4],R11=w2c[5],R12=w2c[6],T1=w2c[7];
    const float R20=w2c[8],R21=w2c[9],R22=w2c[10],T2=w2c[11];
    const float k00=ck[0],k02=ck[2],k11=ck[4],k12=ck[5];
    const float n0=vo[0]+1e-3f, n1=vo[1]+1e-3f, n2=vo[2]+1e-3f;
    const float f0=vo[0]+ss[0]-1e-3f, f1=vo[1]+ss[1]-1e-3f, f2=vo[2]+ss[2]-1e-3f;
    const float cv0=cvr[0],cv1=cvr[1],cv2=cvr[2],cv3=cvr[3],cv4=cvr[4],cv5=cvr[5];
    const float i30=1.0f/(cv3-cv0), i41=1.0f/(cv4-cv1), i52=1.0f/(cv5-cv2);
    const float qtr = R00 + R11 + R22;
    const float qw = sqrtf(fmaxf(qtr + 1.0f, 1e-8f)) * 0.5f;
    const float qi4 = 0.25f / qw;
    const float qx = (R21-R12)*qi4, qy=(R02-R20)*qi4, qz=(R10-R01)*qi4;

    __syncthreads();   // weight images visible; ONLY barrier in the kernel

    // ---- initial prefetch of first chunk into registers ----
    int n = blockIdx.x * WPB + wv;
    bool have = (n < NCH);
    float4 pf[7];
    {
        const int pc = have ? n : 0;
        const float4* g4 = (const float4*)(gp + (long)pc * 1600);
        #pragma unroll
        for (int i = 0; i < 7; ++i) {
            int k = l + i*64;
            if (k < 400) pf[i] = g4[k];
        }
    }

    // ---- per-wave free-running loop over 64-row chunks ----
    while (have) {
        const long Rb = (long)n * 64;
        const long R  = Rb + l;

        // -- publish prefetched gp tile to wave-private LDS --
        {
            float4* x4 = (float4*)xf;
            #pragma unroll
            for (int i = 0; i < 7; ++i) {
                int k = l + i*64;
                if (k < 400) x4[k] = pf[i];
            }
        }

        // -- own row from LDS --
        float v[25];
        #pragma unroll
        for (int j = 0; j < 25; ++j) v[j] = xf[l*25 + j];

        // -- geometry --
        const float x=v[0], y=v[1], zz=v[2];
        const float c0 = R00*x + R01*y + R02*zz + T0;
        const float c1 = R10*x + R11*y + R12*zz + T1;
        const float c2 = R20*x + R21*y + R22*zz + T2;

        bool m1 = c2 > 1e-6f;
        float zc = m1 ? c2 : 1e-6f;
        float fpx = k00 * c0 / zc + k02;
        float fpy = k11 * c1 / zc + k12;
        bool m2 = (fpx >= 0.f) && (fpx < 640.f) && (fpy >= 0.f) && (fpy < 480.f);
        bool mall = m1 && m2;
        bool gpm = (x>n0)&&(x<f0)&&(y>n1)&&(y<f1)&&(zz>n2)&&(zz<f2);
        bool mdet = mall && gpm;
        float tag = (v[23] == 1.0f) ? 0.5f : 0.0f;
        if (!mdet) tag = 1.0f;
        bool gm = (c0>=cv0)&&(c0<=cv3)&&(c1>=cv1)&&(c1<=cv4)&&(c2>=cv2)&&(c2<=cv5);
        bool reuse = gpm && gm;

        oM[R] = reuse ? 1.0f : 0.0f;
        oT[R] = reuse ? tag : 0.0f;
        smk[l] = reuse ? 1.0f : 0.0f;

        // df (fp32)
        float czs = (fabsf(c2) < 1e-6f) ? 1e-6f : c2;
        float px = k00*c0/czs + k02;
        float py = k11*c1/czs + k12;
        int ix = (int)fminf(fmaxf(px, 0.f), 639.f);
        int iy = (int)fminf(fmaxf(py, 0.f), 479.f);
        float d0g = zbuf[iy*640 + ix];
        dfp[l] = make_float2(d0g, c2);

        // -- patch col 24 in LDS tile, then coalesced oP copy --
        xf[l*25 + 24] = gpm ? 1.0f : v[24];
        {
            float4* pd = (float4*)(oP + Rb * 25);
            const float4* x4 = (const float4*)xf;
            #pragma unroll
            for (int i = 0; i < 7; ++i) {
                int k = l + i*64;
                if (k < 400) pd[k] = x4[k];
            }
        }

        // -- anchor --
        float ar[23];
        if (reuse) {
            float p0=v[6], p1=v[7], p2=v[8], p3=v[9];
            ar[0] = sis((c0 - cv0) * i30);
            ar[1] = sis((c1 - cv1) * i41);
            ar[2] = sis((c2 - cv2) * i52);
            ar[3] = sis(v[3]); ar[4] = sis(v[4]); ar[5] = sis(v[5]);
            ar[6] = qw*p0 - qx*p1 - qy*p2 - qz*p3;
            ar[7] = qw*p1 + qx*p0 + qy*p3 - qz*p2;
            ar[8] = qw*p2 - qx*p3 + qy*p0 + qz*p1;
            ar[9] = qw*p3 + qx*p2 - qy*p1 + qz*p0;
            ar[10] = sis(v[10]);
            #pragma unroll
            for (int j = 0; j < 12; ++j) ar[11+j] = v[11+j];
        } else {
            #pragma unroll
            for (int j = 0; j < 23; ++j) ar[j] = 0.0f;
        }

        // -- anchors into LDS tile (overwrites gp tile), coalesced oA copy --
        #pragma unroll
        for (int j = 0; j < 23; ++j) xf[l*23 + j] = ar[j];
        {
            float4* ad = (float4*)(oA + Rb * 23);
            const float4* x4 = (const float4*)xf;
            #pragma unroll
            for (int i = 0; i < 6; ++i) {
                int k = l + i*64;
                if (k < 368) ad[k] = x4[k];
            }
        }

        // -- AN image: own row l, 32 cols bf16 (23 real), swizzled --
        {
            uint4 a0u, a1u, a2u, a3u;
            a0u.x=cvtpk(ar[0],ar[1]);   a0u.y=cvtpk(ar[2],ar[3]);
            a0u.z=cvtpk(ar[4],ar[5]);   a0u.w=cvtpk(ar[6],ar[7]);
            a1u.x=cvtpk(ar[8],ar[9]);   a1u.y=cvtpk(ar[10],ar[11]);
            a1u.z=cvtpk(ar[12],ar[13]); a1u.w=cvtpk(ar[14],ar[15]);
            a2u.x=cvtpk(ar[16],ar[17]); a2u.y=cvtpk(ar[18],ar[19]);
            a2u.z=cvtpk(ar[20],ar[21]); a2u.w=cvtpk(ar[22],0.0f);
            a3u.x=0u; a3u.y=0u; a3u.z=0u; a3u.w=0u;
            char* anr = wlds + ANB + l*64;
            *(uint4*)(anr + ((0 ^ (l&3))<<4)) = a0u;
            *(uint4*)(anr + ((1 ^ (l&3))<<4)) = a1u;
            *(uint4*)(anr + ((2 ^ (l&3))<<4)) = a2u;
            *(uint4*)(anr + ((3 ^ (l&3))<<4)) = a3u;
        }

        // -- claim next chunk + issue its prefetch (hides under strips) --
        int nx;
        if (usews) {
            int nn = 0;
            if (l == 0) nn = atomicAdd(ctr, 1);
            nx = NSTATIC + __shfl(nn, 0);
        } else {
            nx = n + NSTATIC;
        }
        const bool hn = (nx < NCH);
        {
            const int pc = hn ? nx : 0;
            const float4* g4 = (const float4*)(gp + (long)pc * 1600);
            #pragma unroll
            for (int i = 0; i < 7; ++i) {
                int k = l + i*64;
                if (k < 400) pf[i] = g4[k];
            }
        }

        // ---- 4 strips of 16 rows: H1 -> GEMM1 -> GEMM2 -> coalesced oI ----
        for (int s = 0; s < 4; ++s) {
            // H1 strip: lane computes row (l>>2)'s cols sub*16..+15
            {
                const int rr = l >> 2;
                float2 dfv = dfp[16*s + rr];
                float h[16];
                #pragma unroll
                for (int gi = 0; gi < 4; ++gi) {
                    h[gi*4+0] = fmaxf(fmaf(dfv.x, w1a[gi].x, fmaf(dfv.y, w1b[gi].x, b1r[gi].x)), 0.f);
                    h[gi*4+1] = fmaxf(fmaf(dfv.x, w1a[gi].y, fmaf(dfv.y, w1b[gi].y, b1r[gi].y)), 0.f);
                    h[gi*4+2] = fmaxf(fmaf(dfv.x, w1a[gi].z, fmaf(dfv.y, w1b[gi].z, b1r[gi].z)), 0.f);
                    h[gi*4+3] = fmaxf(fmaf(dfv.x, w1a[gi].w, fmaf(dfv.y, w1b[gi].w, b1r[gi].w)), 0.f);
                }
                uint4 pa, pb;
                pa.x = cvtpk(h[0],h[1]);   pa.y = cvtpk(h[2],h[3]);
                pa.z = cvtpk(h[4],h[5]);   pa.w = cvtpk(h[6],h[7]);
                pb.x = cvtpk(h[8],h[9]);   pb.y = cvtpk(h[10],h[11]);
                pb.z = cvtpk(h[12],h[13]); pb.w = cvtpk(h[14],h[15]);
                char* h1r = wlds + H1S + rr*128;
                *(uint4*)(h1r + (((2*sub  ) ^ (rr&7))<<4)) = pa;
                *(uint4*)(h1r + (((2*sub+1) ^ (rr&7))<<4)) = pb;
            }

            // GEMM1: H2s[la][128] = relu(H1s[la] @ W2 + b2)
            {
                short8 hb0 = *(short8*)(wlds + H1S + la*128 + (((lb  ) ^ (la&7))<<4));
                short8 hb1 = *(short8*)(wlds + H1S + la*128 + (((lb+4) ^ (la&7))<<4));
                #pragma unroll
                for (int ct = 0; ct < 8; ++ct) {
                    const int cc = ct*16 + la;
                    short8 a0 = *(short8*)(lds + W2T_OFF + cc*128 + (((lb  ) ^ (cc&7))<<4));
                    short8 a1 = *(short8*)(lds + W2T_OFF + cc*128 + (((lb+4) ^ (cc&7))<<4));
                    f32x4 acc = {0.f, 0.f, 0.f, 0.f};
                    acc = __builtin_amdgcn_mfma_f32_16x16x32_bf16(a0, hb0, acc, 0, 0, 0);
                    acc = __builtin_amdgcn_mfma_f32_16x16x32_bf16(a1, hb1, acc, 0, 0, 0);
                    float4 bb = *(float4*)&sB2[ct*16 + lb*4];
                    float e0 = fmaxf(acc[0] + bb.x, 0.f);
                    float e1 = fmaxf(acc[1] + bb.y, 0.f);
                    float e2 = fmaxf(acc[2] + bb.z, 0.f);
                    float e3 = fmaxf(acc[3] + bb.w, 0.f);
                    uint2 pk; pk.x = cvtpk(e0, e1); pk.y = cvtpk(e2, e3);
                    const int gg = ct*2 + (lb>>1);
                    *(uint2*)(wlds + H2S + la*256 + ((gg ^ la)<<4) + (lb&1)*8) = pk;
                }
            }

            // GEMM2: rows 16s+la; stage to X (stride-104 f32), coalesced oI copy
            {
                short8 B0 = *(short8*)(wlds + H2S + la*256 + ((( 0 + lb) ^ la)<<4));
                short8 B1 = *(short8*)(wlds + H2S + la*256 + ((( 4 + lb) ^ la)<<4));
                short8 B2v= *(short8*)(wlds + H2S + la*256 + ((( 8 + lb) ^ la)<<4));
                short8 B3 = *(short8*)(wlds + H2S + la*256 + (((12 + lb) ^ la)<<4));
                const int row = 16*s + la;
                short8 bA = *(short8*)(wlds + ANB + row*64 + ((lb ^ (row&3))<<4));
                float mk = smk[row];
                #pragma unroll
                for (int ct = 0; ct < 6; ++ct) {
                    const int cc = ct*16 + la;
                    f32x4 acc = {0.f, 0.f, 0.f, 0.f};
                    short8 A0 = *(short8*)(lds + W3T_OFF + cc*256 + ((( 0 + lb) ^ (cc&15))<<4));
                    short8 A1 = *(short8*)(lds + W3T_OFF + cc*256 + ((( 4 + lb) ^ (cc&15))<<4));
                    short8 A2 = *(short8*)(lds + W3T_OFF + cc*256 + ((( 8 + lb) ^ (cc&15))<<4));
                    short8 A3 = *(short8*)(lds + W3T_OFF + cc*256 + (((12 + lb) ^ (cc&15))<<4));
                    acc = __builtin_amdgcn_mfma_f32_16x16x32_bf16(A0, B0, acc, 0, 0, 0);
                    acc = __builtin_amdgcn_mfma_f32_16x16x32_bf16(A1, B1, acc, 0, 0, 0);
                    acc = __builtin_amdgcn_mfma_f32_16x16x32_bf16(A2, B2v, acc, 0, 0, 0);
                    acc = __builtin_amdgcn_mfma_f32_16x16x32_bf16(A3, B3, acc, 0, 0, 0);
                    short8 Aw = *(short8*)(lds + WIT_OFF + cc*64 + ((lb ^ (cc&3))<<4));
                    acc = __builtin_amdgcn_mfma_f32_16x16x32_bf16(Aw, bA, acc, 0, 0, 0);
                    float4 bb = *(float4*)&sBC[ct*16 + lb*4];
                    float4 o;
                    o.x = (mk != 0.f) ? acc[0] + bb.x : 0.f;
                    o.y = (mk != 0.f) ? acc[1] + bb.y : 0.f;
                    o.z = (mk != 0.f) ? acc[2] + bb.z : 0.f;
                    o.w = (mk != 0.f) ? acc[3] + bb.w : 0.f;
                    *(float4*)&xf[la*104 + ct*16 + lb*4] = o;   // stage (X dead now)
                }
                // coalesced oI copy: 6 x float4 per lane (384 float4 = 16x96 f32)
                float* obase = oI + (Rb + 16*s) * 96;
                #pragma unroll
                for (int i = 0; i < 6; ++i) {
                    int k = l + i*64;           // 0..383
                    int rw = k / 24;            // = (4k)/96
                    int col = 4*k - 96*rw;
                    float4 vv = *(const float4*)&xf[rw*104 + col];
                    *(float4*)(obase + 4*k) = vv;
                }
            }
        }

        n = nx;
        have = hn;
    }
}

extern "C" void kernel_launch(void* const* d_in, const int* in_sizes, int n_in,
                              void* d_out, int out_size, void* d_ws, size_t ws_size,
                              hipStream_t stream)
{
    const float* gp  = (const float*)d_in[0];
    const float* zb  = (const float*)d_in[2];
    const float* w2c = (const float*)d_in[3];
    const float* ck  = (const float*)d_in[4];
    const float* vo  = (const float*)d_in[5];
    const float* ss  = (const float*)d_in[6];
    const float* cvr = (const float*)d_in[7];
    const float* Wi  = (const float*)d_in[8];
    const float* bi  = (const float*)d_in[9];
    const float* W1  = (const float*)d_in[10];
    const float* b1  = (const float*)d_in[11];
    const float* W2  = (const float*)d_in[12];
    const float* b2  = (const float*)d_in[13];
    const float* W3  = (const float*)d_in[14];
    const float* b3  = (const float*)d_in[15];

    float* out = (float*)d_out;
    const long N = NG;
    float* oA = out;               // (N,23)
    float* oT = out + 23L * N;     // (N,)
    float* oI = out + 24L * N;     // (N,96)
    float* oP = out + 120L * N;    // (N,25)
    float* oM = out + 145L * N;    // (N,)

    int usews = (ws_size >= 4) ? 1 : 0;
    int* ctr = (int*)d_ws;
    if (usews) hipMemsetAsync(d_ws, 0, 4, stream);

    k_main<<<GRID, BLK, 0, stream>>>(gp, zb, w2c, ck, vo, ss, cvr,
                                     W1, b1, W2, b2, W3, b3, Wi, bi,
                                     oA, oT, oI, oP, oM, ctr, usews);
}

// Round 12
// 188.515 us; speedup vs baseline: 1.0038x; 1.0038x over previous
//
#include <hip/hip_runtime.h>
#include <math.h>

#define NG 800000        // = 12500 chunks of 64 rows
#define NCH 12500
#define GRID 256
#define BLK 512
#define WPB 8
#define NSTATIC 2048     // GRID * WPB

typedef __attribute__((ext_vector_type(8))) short short8;
typedef __attribute__((ext_vector_type(4))) float f32x4;

// ---- shared LDS layout (bytes) ----
#define W2T_OFF 0        // 16384  [c=128][k=64] bf16 swz
#define W3T_OFF 16384    // 24576  [c=96][k=128] bf16 swz
#define WIT_OFF 40960    //  6144  [c=96][k=32]  bf16 swz
#define B2_OFF  47104    //   512  f32[128]
#define BC_OFF  47616    //   384  f32[96]
#define WV_OFF  48128    // 8 waves x 11264
// per-wave region (11264 B):
#define X_OFF 0          //  6400  gp tile -> oA staging -> (H1S,H2S) in strips
#define H1S   0          //  alias: 2048  [16][64]  bf16 swz strip
#define H2S   2048       //  alias: 4096  [16][128] bf16 swz strip
#define ANB   6400       //  4096  [64][32] bf16 swz
#define DFP   10496      //   512  float2[64]
#define SMK   11008      //   256  float[64]
#define WV_SZ 11264
#define LDS_TOT (WV_OFF + WPB * WV_SZ)   // 138240

__device__ __forceinline__ float sis(float t) {
    t = fminf(fmaxf(t, 0.01f), 0.99f);
    return logf(t / (1.0f - t));
}
__device__ __forceinline__ unsigned short f2bf(float f) {
    unsigned int u = __float_as_uint(f);
    return (unsigned short)((u + 0x7FFFu + ((u >> 16) & 1u)) >> 16);
}
__device__ __forceinline__ unsigned int cvtpk(float a, float b) {
    unsigned int r;
    asm("v_cvt_pk_bf16_f32 %0, %1, %2" : "=v"(r) : "v"(a), "v"(b));
    return r;
}

__global__ __launch_bounds__(BLK, 2) void k_main(
    const float* __restrict__ gp,
    const float* __restrict__ zbuf,
    const float* __restrict__ w2c,
    const float* __restrict__ ck,
    const float* __restrict__ vo,
    const float* __restrict__ ss,
    const float* __restrict__ cvr,
    const float* __restrict__ W1, const float* __restrict__ b1,
    const float* __restrict__ W2, const float* __restrict__ b2,
    const float* __restrict__ W3, const float* __restrict__ b3,
    const float* __restrict__ Wi, const float* __restrict__ bi,
    float* __restrict__ oA, float* __restrict__ oT,
    float* __restrict__ oI, float* __restrict__ oP, float* __restrict__ oM,
    int* __restrict__ ctr, int usews)
{
    __shared__ __align__(16) char lds[LDS_TOT];
    float* sB2 = (float*)(lds + B2_OFF);
    float* sBC = (float*)(lds + BC_OFF);

    const int t   = threadIdx.x;
    const int wv  = t >> 6;
    const int l   = t & 63;
    const int la  = l & 15;
    const int lb  = l >> 4;
    const int sub = l & 3;
    char* wlds = lds + WV_OFF + wv * WV_SZ;
    float*  xf  = (float*)(wlds + X_OFF);
    float2* dfp = (float2*)(wlds + DFP);
    float*  smk = (float*)(wlds + SMK);

    // ---- build shared weight images (once per block) ----
    for (int idx = t; idx < 8192; idx += BLK) {            // W2T
        int k = idx >> 7, c = idx & 127;
        *(unsigned short*)(lds + W2T_OFF + c*128 + (((k>>3) ^ (c&7))<<4) + (k&7)*2)
            = f2bf(W2[idx]);
    }
    for (int idx = t; idx < 12288; idx += BLK) {           // W3T
        int k = idx / 96, c = idx - k*96;
        *(unsigned short*)(lds + W3T_OFF + c*256 + (((k>>3) ^ (c&15))<<4) + (k&7)*2)
            = f2bf(W3[idx]);
    }
    for (int idx = t; idx < 3072; idx += BLK) {            // WIT
        int c = idx >> 5, k = idx & 31;
        float val = (k < 23) ? Wi[k*96 + c] : 0.0f;
        *(unsigned short*)(lds + WIT_OFF + c*64 + (((k>>3) ^ (c&3))<<4) + (k&7)*2)
            = f2bf(val);
    }
    if (t < 128) sB2[t] = b2[t];
    if (t < 96)  sBC[t] = b3[t] + bi[t];

    // per-lane W1/b1 column block (cols sub*16..sub*16+15) in registers
    float4 w1a[4], w1b[4], b1r[4];
    #pragma unroll
    for (int gi = 0; gi < 4; ++gi) {
        w1a[gi] = *(const float4*)&W1[sub*16 + gi*4];
        w1b[gi] = *(const float4*)&W1[64 + sub*16 + gi*4];
        b1r[gi] = *(const float4*)&b1[sub*16 + gi*4];
    }

    // uniforms
    const float R00=w2c[0],R01=w2c[1],R02=w2c[2],T0=w2c[3];
    const float R10=w2c[4],R11=w2c[5],R12=w2c[6],T1=w2c[7];
    const float R20=w2c[8],R21=w2c[9],R22=w2c[10],T2=w2c[11];
    const float k00=ck[0],k02=ck[2],k11=ck[4],k12=ck[5];
    const float n0=vo[0]+1e-3f, n1=vo[1]+1e-3f, n2=vo[2]+1e-3f;
    const float f0=vo[0]+ss[0]-1e-3f, f1=vo[1]+ss[1]-1e-3f, f2=vo[2]+ss[2]-1e-3f;
    const float cv0=cvr[0],cv1=cvr[1],cv2=cvr[2],cv3=cvr[3],cv4=cvr[4],cv5=cvr[5];
    const float i30=1.0f/(cv3-cv0), i41=1.0f/(cv4-cv1), i52=1.0f/(cv5-cv2);
    const float qtr = R00 + R11 + R22;
    const float qw = sqrtf(fmaxf(qtr + 1.0f, 1e-8f)) * 0.5f;
    const float qi4 = 0.25f / qw;
    const float qx = (R21-R12)*qi4, qy=(R02-R20)*qi4, qz=(R10-R01)*qi4;

    __syncthreads();   // weight images visible; ONLY barrier in the kernel

    // ---- initial prefetch of first chunk into registers ----
    int n = blockIdx.x * WPB + wv;
    bool have = (n < NCH);
    float4 pf[7];
    {
        const int pc = have ? n : 0;
        const float4* g4 = (const float4*)(gp + (long)pc * 1600);
        #pragma unroll
        for (int i = 0; i < 7; ++i) {
            int k = l + i*64;
            if (k < 400) pf[i] = g4[k];
        }
    }

    // ---- per-wave free-running loop over 64-row chunks ----
    while (have) {
        const long Rb = (long)n * 64;
        const long R  = Rb + l;

        // -- publish prefetched gp tile to wave-private LDS --
        {
            float4* x4 = (float4*)xf;
            #pragma unroll
            for (int i = 0; i < 7; ++i) {
                int k = l + i*64;
                if (k < 400) x4[k] = pf[i];
            }
        }

        // -- own row from LDS (conflict-free b32 reads) --
        float v[25];
        #pragma unroll
        for (int j = 0; j < 25; ++j) v[j] = xf[l*25 + j];

        // -- geometry --
        const float x=v[0], y=v[1], zz=v[2];
        const float c0 = R00*x + R01*y + R02*zz + T0;
        const float c1 = R10*x + R11*y + R12*zz + T1;
        const float c2 = R20*x + R21*y + R22*zz + T2;

        bool m1 = c2 > 1e-6f;
        float zc = m1 ? c2 : 1e-6f;
        float fpx = k00 * c0 / zc + k02;
        float fpy = k11 * c1 / zc + k12;
        bool m2 = (fpx >= 0.f) && (fpx < 640.f) && (fpy >= 0.f) && (fpy < 480.f);
        bool mall = m1 && m2;
        bool gpm = (x>n0)&&(x<f0)&&(y>n1)&&(y<f1)&&(zz>n2)&&(zz<f2);
        bool mdet = mall && gpm;
        float tag = (v[23] == 1.0f) ? 0.5f : 0.0f;
        if (!mdet) tag = 1.0f;
        bool gm = (c0>=cv0)&&(c0<=cv3)&&(c1>=cv1)&&(c1<=cv4)&&(c2>=cv2)&&(c2<=cv5);
        bool reuse = gpm && gm;

        oM[R] = reuse ? 1.0f : 0.0f;
        oT[R] = reuse ? tag : 0.0f;
        smk[l] = reuse ? 1.0f : 0.0f;

        // df (fp32)
        float czs = (fabsf(c2) < 1e-6f) ? 1e-6f : c2;
        float px = k00*c0/czs + k02;
        float py = k11*c1/czs + k12;
        int ix = (int)fminf(fmaxf(px, 0.f), 639.f);
        int iy = (int)fminf(fmaxf(py, 0.f), 479.f);
        float d0g = zbuf[iy*640 + ix];
        dfp[l] = make_float2(d0g, c2);

        // -- patch col 24 in the LDS tile, then coalesced oP copy --
        xf[l*25 + 24] = gpm ? 1.0f : v[24];
        {
            float4* pd = (float4*)(oP + Rb * 25);
            const float4* x4 = (const float4*)xf;
            #pragma unroll
            for (int i = 0; i < 7; ++i) {
                int k = l + i*64;
                if (k < 400) pd[k] = x4[k];
            }
        }

        // -- anchor --
        float ar[23];
        if (reuse) {
            float p0=v[6], p1=v[7], p2=v[8], p3=v[9];
            ar[0] = sis((c0 - cv0) * i30);
            ar[1] = sis((c1 - cv1) * i41);
            ar[2] = sis((c2 - cv2) * i52);
            ar[3] = sis(v[3]); ar[4] = sis(v[4]); ar[5] = sis(v[5]);
            ar[6] = qw*p0 - qx*p1 - qy*p2 - qz*p3;
            ar[7] = qw*p1 + qx*p0 + qy*p3 - qz*p2;
            ar[8] = qw*p2 - qx*p3 + qy*p0 + qz*p1;
            ar[9] = qw*p3 + qx*p2 - qy*p1 + qz*p0;
            ar[10] = sis(v[10]);
            #pragma unroll
            for (int j = 0; j < 12; ++j) ar[11+j] = v[11+j];
        } else {
            #pragma unroll
            for (int j = 0; j < 23; ++j) ar[j] = 0.0f;
        }

        // -- anchors into LDS tile (overwrites gp tile), coalesced oA copy --
        #pragma unroll
        for (int j = 0; j < 23; ++j) xf[l*23 + j] = ar[j];
        {
            float4* ad = (float4*)(oA + Rb * 23);
            const float4* x4 = (const float4*)xf;
            #pragma unroll
            for (int i = 0; i < 6; ++i) {
                int k = l + i*64;
                if (k < 368) ad[k] = x4[k];
            }
        }

        // -- AN image: own row l, 32 cols bf16 (23 real), swizzled --
        {
            uint4 a0u, a1u, a2u, a3u;
            a0u.x=cvtpk(ar[0],ar[1]);   a0u.y=cvtpk(ar[2],ar[3]);
            a0u.z=cvtpk(ar[4],ar[5]);   a0u.w=cvtpk(ar[6],ar[7]);
            a1u.x=cvtpk(ar[8],ar[9]);   a1u.y=cvtpk(ar[10],ar[11]);
            a1u.z=cvtpk(ar[12],ar[13]); a1u.w=cvtpk(ar[14],ar[15]);
            a2u.x=cvtpk(ar[16],ar[17]); a2u.y=cvtpk(ar[18],ar[19]);
            a2u.z=cvtpk(ar[20],ar[21]); a2u.w=cvtpk(ar[22],0.0f);
            a3u.x=0u; a3u.y=0u; a3u.z=0u; a3u.w=0u;
            char* anr = wlds + ANB + l*64;
            *(uint4*)(anr + ((0 ^ (l&3))<<4)) = a0u;
            *(uint4*)(anr + ((1 ^ (l&3))<<4)) = a1u;
            *(uint4*)(anr + ((2 ^ (l&3))<<4)) = a2u;
            *(uint4*)(anr + ((3 ^ (l&3))<<4)) = a3u;
        }

        // -- claim next chunk + issue its prefetch (drains under strips) --
        int nx;
        if (usews) {
            int nn = 0;
            if (l == 0) nn = atomicAdd(ctr, 1);
            nx = NSTATIC + __shfl(nn, 0);
        } else {
            nx = n + NSTATIC;
        }
        const bool hn = (nx < NCH);
        {
            const int pc = hn ? nx : 0;
            const float4* g4 = (const float4*)(gp + (long)pc * 1600);
            #pragma unroll
            for (int i = 0; i < 7; ++i) {
                int k = l + i*64;
                if (k < 400) pf[i] = g4[k];
            }
        }

        // ---- 4 strips of 16 rows: H1 -> GEMM1 -> GEMM2 ----
        for (int s = 0; s < 4; ++s) {
            // H1 strip: lane computes row (l>>2)'s cols sub*16..+15
            {
                const int rr = l >> 2;
                float2 dfv = dfp[16*s + rr];
                float h[16];
                #pragma unroll
                for (int gi = 0; gi < 4; ++gi) {
                    h[gi*4+0] = fmaxf(fmaf(dfv.x, w1a[gi].x, fmaf(dfv.y, w1b[gi].x, b1r[gi].x)), 0.f);
                    h[gi*4+1] = fmaxf(fmaf(dfv.x, w1a[gi].y, fmaf(dfv.y, w1b[gi].y, b1r[gi].y)), 0.f);
                    h[gi*4+2] = fmaxf(fmaf(dfv.x, w1a[gi].z, fmaf(dfv.y, w1b[gi].z, b1r[gi].z)), 0.f);
                    h[gi*4+3] = fmaxf(fmaf(dfv.x, w1a[gi].w, fmaf(dfv.y, w1b[gi].w, b1r[gi].w)), 0.f);
                }
                uint4 pa, pb;
                pa.x = cvtpk(h[0],h[1]);   pa.y = cvtpk(h[2],h[3]);
                pa.z = cvtpk(h[4],h[5]);   pa.w = cvtpk(h[6],h[7]);
                pb.x = cvtpk(h[8],h[9]);   pb.y = cvtpk(h[10],h[11]);
                pb.z = cvtpk(h[12],h[13]); pb.w = cvtpk(h[14],h[15]);
                char* h1r = wlds + H1S + rr*128;
                *(uint4*)(h1r + (((2*sub  ) ^ (rr&7))<<4)) = pa;
                *(uint4*)(h1r + (((2*sub+1) ^ (rr&7))<<4)) = pb;
            }

            // GEMM1: H2s[la][128] = relu(H1s[la] @ W2 + b2)
            {
                short8 hb0 = *(short8*)(wlds + H1S + la*128 + (((lb  ) ^ (la&7))<<4));
                short8 hb1 = *(short8*)(wlds + H1S + la*128 + (((lb+4) ^ (la&7))<<4));
                #pragma unroll
                for (int ct = 0; ct < 8; ++ct) {
                    const int cc = ct*16 + la;
                    short8 a0 = *(short8*)(lds + W2T_OFF + cc*128 + (((lb  ) ^ (cc&7))<<4));
                    short8 a1 = *(short8*)(lds + W2T_OFF + cc*128 + (((lb+4) ^ (cc&7))<<4));
                    f32x4 acc = {0.f, 0.f, 0.f, 0.f};
                    acc = __builtin_amdgcn_mfma_f32_16x16x32_bf16(a0, hb0, acc, 0, 0, 0);
                    acc = __builtin_amdgcn_mfma_f32_16x16x32_bf16(a1, hb1, acc, 0, 0, 0);
                    float4 bb = *(float4*)&sB2[ct*16 + lb*4];
                    float e0 = fmaxf(acc[0] + bb.x, 0.f);
                    float e1 = fmaxf(acc[1] + bb.y, 0.f);
                    float e2 = fmaxf(acc[2] + bb.z, 0.f);
                    float e3 = fmaxf(acc[3] + bb.w, 0.f);
                    uint2 pk; pk.x = cvtpk(e0, e1); pk.y = cvtpk(e2, e3);
                    const int gg = ct*2 + (lb>>1);
                    *(uint2*)(wlds + H2S + la*256 + ((gg ^ la)<<4) + (lb&1)*8) = pk;
                }
            }

            // GEMM2: oI rows 16s+la = H2s @ W3 + AN @ Wi + bc, masked
            {
                short8 B0 = *(short8*)(wlds + H2S + la*256 + ((( 0 + lb) ^ la)<<4));
                short8 B1 = *(short8*)(wlds + H2S + la*256 + ((( 4 + lb) ^ la)<<4));
                short8 B2v= *(short8*)(wlds + H2S + la*256 + ((( 8 + lb) ^ la)<<4));
                short8 B3 = *(short8*)(wlds + H2S + la*256 + (((12 + lb) ^ la)<<4));
                const int row = 16*s + la;
                short8 bA = *(short8*)(wlds + ANB + row*64 + ((lb ^ (row&3))<<4));
                float mk = smk[row];
                float* orow = oI + (Rb + row) * 96;
                #pragma unroll
                for (int ct = 0; ct < 6; ++ct) {
                    const int cc = ct*16 + la;
                    f32x4 acc = {0.f, 0.f, 0.f, 0.f};
                    short8 A0 = *(short8*)(lds + W3T_OFF + cc*256 + ((( 0 + lb) ^ (cc&15))<<4));
                    short8 A1 = *(short8*)(lds + W3T_OFF + cc*256 + ((( 4 + lb) ^ (cc&15))<<4));
                    short8 A2 = *(short8*)(lds + W3T_OFF + cc*256 + ((( 8 + lb) ^ (cc&15))<<4));
                    short8 A3 = *(short8*)(lds + W3T_OFF + cc*256 + (((12 + lb) ^ (cc&15))<<4));
                    acc = __builtin_amdgcn_mfma_f32_16x16x32_bf16(A0, B0, acc, 0, 0, 0);
                    acc = __builtin_amdgcn_mfma_f32_16x16x32_bf16(A1, B1, acc, 0, 0, 0);
                    acc = __builtin_amdgcn_mfma_f32_16x16x32_bf16(A2, B2v, acc, 0, 0, 0);
                    acc = __builtin_amdgcn_mfma_f32_16x16x32_bf16(A3, B3, acc, 0, 0, 0);
                    short8 Aw = *(short8*)(lds + WIT_OFF + cc*64 + ((lb ^ (cc&3))<<4));
                    acc = __builtin_amdgcn_mfma_f32_16x16x32_bf16(Aw, bA, acc, 0, 0, 0);
                    float4 bb = *(float4*)&sBC[ct*16 + lb*4];
                    float4 o;
                    o.x = (mk != 0.f) ? acc[0] + bb.x : 0.f;
                    o.y = (mk != 0.f) ? acc[1] + bb.y : 0.f;
                    o.z = (mk != 0.f) ? acc[2] + bb.z : 0.f;
                    o.w = (mk != 0.f) ? acc[3] + bb.w : 0.f;
                    *(float4*)(orow + ct*16 + lb*4) = o;
                }
            }
        }

        n = nx;
        have = hn;
    }
}

extern "C" void kernel_launch(void* const* d_in, const int* in_sizes, int n_in,
                              void* d_out, int out_size, void* d_ws, size_t ws_size,
                              hipStream_t stream)
{
    const float* gp  = (const float*)d_in[0];
    const float* zb  = (const float*)d_in[2];
    const float* w2c = (const float*)d_in[3];
    const float* ck  = (const float*)d_in[4];
    const float* vo  = (const float*)d_in[5];
    const float* ss  = (const float*)d_in[6];
    const float* cvr = (const float*)d_in[7];
    const float* Wi  = (const float*)d_in[8];
    const float* bi  = (const float*)d_in[9];
    const float* W1  = (const float*)d_in[10];
    const float* b1  = (const float*)d_in[11];
    const float* W2  = (const float*)d_in[12];
    const float* b2  = (const float*)d_in[13];
    const float* W3  = (const float*)d_in[14];
    const float* b3  = (const float*)d_in[15];

    float* out = (float*)d_out;
    const long N = NG;
    float* oA = out;               // (N,23)
    float* oT = out + 23L * N;     // (N,)
    float* oI = out + 24L * N;     // (N,96)
    float* oP = out + 120L * N;    // (N,25)
    float* oM = out + 145L * N;    // (N,)

    int usews = (ws_size >= 4) ? 1 : 0;
    int* ctr = (int*)d_ws;
    if (usews) hipMemsetAsync(d_ws, 0, 4, stream);

    k_main<<<GRID, BLK, 0, stream>>>(gp, zb, w2c, ck, vo, ss, cvr,
                                     W1, b1, W2, b2, W3, b3, Wi, bi,
                                     oA, oT, oI, oP, oM, ctr, usews);
}

// Round 13
// 188.329 us; speedup vs baseline: 1.0048x; 1.0010x over previous
//
#include <hip/hip_runtime.h>
#include <math.h>

#define NG 800000        // = 12500 chunks of 64 rows
#define NCH 12500
#define GRID 256
#define BLK 512
#define WPB 8
#define NSTATIC 2048     // GRID * WPB

typedef __attribute__((ext_vector_type(8))) short short8;
typedef __attribute__((ext_vector_type(4))) float f32x4;

// ---- shared LDS layout (bytes) ----
#define W2T_OFF 0        // 16384  [c=128][k=64] bf16 swz
#define W3T_OFF 16384    // 24576  [c=96][k=128] bf16 swz
#define WIT_OFF 40960    //  6144  [c=96][k=32]  bf16 swz
#define B2_OFF  47104    //   512  f32[128]
#define BC_OFF  47616    //   384  f32[96]
#define WV_OFF  48128    // 8 waves x 11264
// per-wave region (11264 B):
#define X_OFF 0          //  6400  gp tile -> oA staging -> (H1S,H2S) in strips
#define H1S   0          //  alias: 2048  [16][64]  bf16 swz strip
#define H2S   2048       //  alias: 4096  [16][128] bf16 swz strip
#define ANB   6400       //  4096  [64][32] bf16 swz
#define DFP   10496      //   512  float2[64]
#define SMK   11008      //   256  float[64]
#define WV_SZ 11264
#define LDS_TOT (WV_OFF + WPB * WV_SZ)   // 138240

__device__ __forceinline__ float sis(float t) {
    t = fminf(fmaxf(t, 0.01f), 0.99f);
    return logf(t / (1.0f - t));
}
__device__ __forceinline__ unsigned short f2bf(float f) {
    unsigned int u = __float_as_uint(f);
    return (unsigned short)((u + 0x7FFFu + ((u >> 16) & 1u)) >> 16);
}
__device__ __forceinline__ unsigned int cvtpk(float a, float b) {
    unsigned int r;
    asm("v_cvt_pk_bf16_f32 %0, %1, %2" : "=v"(r) : "v"(a), "v"(b));
    return r;
}

__global__ __launch_bounds__(BLK, 2) void k_main(
    const float* __restrict__ gp,
    const float* __restrict__ zbuf,
    const float* __restrict__ w2c,
    const float* __restrict__ ck,
    const float* __restrict__ vo,
    const float* __restrict__ ss,
    const float* __restrict__ cvr,
    const float* __restrict__ W1, const float* __restrict__ b1,
    const float* __restrict__ W2, const float* __restrict__ b2,
    const float* __restrict__ W3, const float* __restrict__ b3,
    const float* __restrict__ Wi, const float* __restrict__ bi,
    float* __restrict__ oA, float* __restrict__ oT,
    float* __restrict__ oI, float* __restrict__ oP, float* __restrict__ oM,
    int* __restrict__ ctr, int usews)
{
    __shared__ __align__(16) char lds[LDS_TOT];
    float* sB2 = (float*)(lds + B2_OFF);
    float* sBC = (float*)(lds + BC_OFF);

    const int t   = threadIdx.x;
    const int wv  = t >> 6;
    const int l   = t & 63;
    const int la  = l & 15;
    const int lb  = l >> 4;
    const int sub = l & 3;
    char* wlds = lds + WV_OFF + wv * WV_SZ;
    float*  xf  = (float*)(wlds + X_OFF);
    float2* dfp = (float2*)(wlds + DFP);
    float*  smk = (float*)(wlds + SMK);

    // ---- build shared weight images (once per block) ----
    for (int idx = t; idx < 8192; idx += BLK) {            // W2T
        int k = idx >> 7, c = idx & 127;
        *(unsigned short*)(lds + W2T_OFF + c*128 + (((k>>3) ^ (c&7))<<4) + (k&7)*2)
            = f2bf(W2[idx]);
    }
    for (int idx = t; idx < 12288; idx += BLK) {           // W3T
        int k = idx / 96, c = idx - k*96;
        *(unsigned short*)(lds + W3T_OFF + c*256 + (((k>>3) ^ (c&15))<<4) + (k&7)*2)
            = f2bf(W3[idx]);
    }
    for (int idx = t; idx < 3072; idx += BLK) {            // WIT
        int c = idx >> 5, k = idx & 31;
        float val = (k < 23) ? Wi[k*96 + c] : 0.0f;
        *(unsigned short*)(lds + WIT_OFF + c*64 + (((k>>3) ^ (c&3))<<4) + (k&7)*2)
            = f2bf(val);
    }
    if (t < 128) sB2[t] = b2[t];
    if (t < 96)  sBC[t] = b3[t] + bi[t];

    // per-lane W1/b1 column block (cols sub*16..sub*16+15) in registers
    float4 w1a[4], w1b[4], b1r[4];
    #pragma unroll
    for (int gi = 0; gi < 4; ++gi) {
        w1a[gi] = *(const float4*)&W1[sub*16 + gi*4];
        w1b[gi] = *(const float4*)&W1[64 + sub*16 + gi*4];
        b1r[gi] = *(const float4*)&b1[sub*16 + gi*4];
    }

    // uniforms
    const float R00=w2c[0],R01=w2c[1],R02=w2c[2],T0=w2c[3];
    const float R10=w2c[4],R11=w2c[5],R12=w2c[6],T1=w2c[7];
    const float R20=w2c[8],R21=w2c[9],R22=w2c[10],T2=w2c[11];
    const float k00=ck[0],k02=ck[2],k11=ck[4],k12=ck[5];
    const float n0=vo[0]+1e-3f, n1=vo[1]+1e-3f, n2=vo[2]+1e-3f;
    const float f0=vo[0]+ss[0]-1e-3f, f1=vo[1]+ss[1]-1e-3f, f2=vo[2]+ss[2]-1e-3f;
    const float cv0=cvr[0],cv1=cvr[1],cv2=cvr[2],cv3=cvr[3],cv4=cvr[4],cv5=cvr[5];
    const float i30=1.0f/(cv3-cv0), i41=1.0f/(cv4-cv1), i52=1.0f/(cv5-cv2);
    const float qtr = R00 + R11 + R22;
    const float qw = sqrtf(fmaxf(qtr + 1.0f, 1e-8f)) * 0.5f;
    const float qi4 = 0.25f / qw;
    const float qx = (R21-R12)*qi4, qy=(R02-R20)*qi4, qz=(R10-R01)*qi4;

    __syncthreads();   // weight images visible; ONLY barrier in the kernel

    // ---- per-wave free-running loop over 64-row chunks ----
    int n = blockIdx.x * WPB + wv;
    while (n < NCH) {
        const long Rb = (long)n * 64;
        const long R  = Rb + l;

        // -- stage gp tile: fully coalesced (400 float4), wave-private LDS --
        {
            const float4* g4 = (const float4*)(gp + Rb * 25);
            float4* x4 = (float4*)xf;
            #pragma unroll
            for (int i = 0; i < 7; ++i) {
                int k = l + i*64;
                if (k < 400) x4[k] = g4[k];
            }
        }

        // -- own row from LDS (conflict-free b32 reads) --
        float v[25];
        #pragma unroll
        for (int j = 0; j < 25; ++j) v[j] = xf[l*25 + j];

        // -- geometry --
        const float x=v[0], y=v[1], zz=v[2];
        const float c0 = R00*x + R01*y + R02*zz + T0;
        const float c1 = R10*x + R11*y + R12*zz + T1;
        const float c2 = R20*x + R21*y + R22*zz + T2;

        bool m1 = c2 > 1e-6f;
        float zc = m1 ? c2 : 1e-6f;
        float fpx = k00 * c0 / zc + k02;
        float fpy = k11 * c1 / zc + k12;
        bool m2 = (fpx >= 0.f) && (fpx < 640.f) && (fpy >= 0.f) && (fpy < 480.f);
        bool mall = m1 && m2;
        bool gpm = (x>n0)&&(x<f0)&&(y>n1)&&(y<f1)&&(zz>n2)&&(zz<f2);
        bool mdet = mall && gpm;
        float tag = (v[23] == 1.0f) ? 0.5f : 0.0f;
        if (!mdet) tag = 1.0f;
        bool gm = (c0>=cv0)&&(c0<=cv3)&&(c1>=cv1)&&(c1<=cv4)&&(c2>=cv2)&&(c2<=cv5);
        bool reuse = gpm && gm;

        oM[R] = reuse ? 1.0f : 0.0f;     // stride-4B: naturally coalesced
        oT[R] = reuse ? tag : 0.0f;
        smk[l] = reuse ? 1.0f : 0.0f;

        // df (fp32)
        float czs = (fabsf(c2) < 1e-6f) ? 1e-6f : c2;
        float px = k00*c0/czs + k02;
        float py = k11*c1/czs + k12;
        int ix = (int)fminf(fmaxf(px, 0.f), 639.f);
        int iy = (int)fminf(fmaxf(py, 0.f), 479.f);
        float d0g = zbuf[iy*640 + ix];
        dfp[l] = make_float2(d0g, c2);

        // -- patch col 24 in the LDS tile, then coalesced oP copy --
        xf[l*25 + 24] = gpm ? 1.0f : v[24];
        {
            float4* pd = (float4*)(oP + Rb * 25);
            const float4* x4 = (const float4*)xf;
            #pragma unroll
            for (int i = 0; i < 7; ++i) {
                int k = l + i*64;
                if (k < 400) pd[k] = x4[k];
            }
        }

        // -- anchor --
        float ar[23];
        if (reuse) {
            float p0=v[6], p1=v[7], p2=v[8], p3=v[9];
            ar[0] = sis((c0 - cv0) * i30);
            ar[1] = sis((c1 - cv1) * i41);
            ar[2] = sis((c2 - cv2) * i52);
            ar[3] = sis(v[3]); ar[4] = sis(v[4]); ar[5] = sis(v[5]);
            ar[6] = qw*p0 - qx*p1 - qy*p2 - qz*p3;
            ar[7] = qw*p1 + qx*p0 + qy*p3 - qz*p2;
            ar[8] = qw*p2 - qx*p3 + qy*p0 + qz*p1;
            ar[9] = qw*p3 + qx*p2 - qy*p1 + qz*p0;
            ar[10] = sis(v[10]);
            #pragma unroll
            for (int j = 0; j < 12; ++j) ar[11+j] = v[11+j];
        } else {
            #pragma unroll
            for (int j = 0; j < 23; ++j) ar[j] = 0.0f;
        }

        // -- anchors into LDS tile (overwrites gp tile), coalesced oA copy --
        #pragma unroll
        for (int j = 0; j < 23; ++j) xf[l*23 + j] = ar[j];
        {
            float4* ad = (float4*)(oA + Rb * 23);
            const float4* x4 = (const float4*)xf;
            #pragma unroll
            for (int i = 0; i < 6; ++i) {
                int k = l + i*64;
                if (k < 368) ad[k] = x4[k];
            }
        }

        // -- AN image: own row l, 32 cols bf16 (23 real), swizzled --
        {
            uint4 a0u, a1u, a2u, a3u;
            a0u.x=cvtpk(ar[0],ar[1]);   a0u.y=cvtpk(ar[2],ar[3]);
            a0u.z=cvtpk(ar[4],ar[5]);   a0u.w=cvtpk(ar[6],ar[7]);
            a1u.x=cvtpk(ar[8],ar[9]);   a1u.y=cvtpk(ar[10],ar[11]);
            a1u.z=cvtpk(ar[12],ar[13]); a1u.w=cvtpk(ar[14],ar[15]);
            a2u.x=cvtpk(ar[16],ar[17]); a2u.y=cvtpk(ar[18],ar[19]);
            a2u.z=cvtpk(ar[20],ar[21]); a2u.w=cvtpk(ar[22],0.0f);
            a3u.x=0u; a3u.y=0u; a3u.z=0u; a3u.w=0u;
            char* anr = wlds + ANB + l*64;
            *(uint4*)(anr + ((0 ^ (l&3))<<4)) = a0u;
            *(uint4*)(anr + ((1 ^ (l&3))<<4)) = a1u;
            *(uint4*)(anr + ((2 ^ (l&3))<<4)) = a2u;
            *(uint4*)(anr + ((3 ^ (l&3))<<4)) = a3u;
        }

        // -- claim next chunk NOW; atomic latency drains under the strips --
        int nx;
        if (usews) {
            int nn = 0;
            if (l == 0) nn = atomicAdd(ctr, 1);
            nx = NSTATIC + __shfl(nn, 0);
        } else {
            nx = n + NSTATIC;
        }

        // ---- 4 strips of 16 rows: H1 -> GEMM1 -> GEMM2 ----
        for (int s = 0; s < 4; ++s) {
            // H1 strip: lane computes row (l>>2)'s cols sub*16..+15
            {
                const int rr = l >> 2;
                float2 dfv = dfp[16*s + rr];
                float h[16];
                #pragma unroll
                for (int gi = 0; gi < 4; ++gi) {
                    h[gi*4+0] = fmaxf(fmaf(dfv.x, w1a[gi].x, fmaf(dfv.y, w1b[gi].x, b1r[gi].x)), 0.f);
                    h[gi*4+1] = fmaxf(fmaf(dfv.x, w1a[gi].y, fmaf(dfv.y, w1b[gi].y, b1r[gi].y)), 0.f);
                    h[gi*4+2] = fmaxf(fmaf(dfv.x, w1a[gi].z, fmaf(dfv.y, w1b[gi].z, b1r[gi].z)), 0.f);
                    h[gi*4+3] = fmaxf(fmaf(dfv.x, w1a[gi].w, fmaf(dfv.y, w1b[gi].w, b1r[gi].w)), 0.f);
                }
                uint4 pa, pb;
                pa.x = cvtpk(h[0],h[1]);   pa.y = cvtpk(h[2],h[3]);
                pa.z = cvtpk(h[4],h[5]);   pa.w = cvtpk(h[6],h[7]);
                pb.x = cvtpk(h[8],h[9]);   pb.y = cvtpk(h[10],h[11]);
                pb.z = cvtpk(h[12],h[13]); pb.w = cvtpk(h[14],h[15]);
                char* h1r = wlds + H1S + rr*128;
                *(uint4*)(h1r + (((2*sub  ) ^ (rr&7))<<4)) = pa;
                *(uint4*)(h1r + (((2*sub+1) ^ (rr&7))<<4)) = pb;
            }

            // GEMM1: H2s[la][128] = relu(H1s[la] @ W2 + b2)
            {
                short8 hb0 = *(short8*)(wlds + H1S + la*128 + (((lb  ) ^ (la&7))<<4));
                short8 hb1 = *(short8*)(wlds + H1S + la*128 + (((lb+4) ^ (la&7))<<4));
                #pragma unroll
                for (int ct = 0; ct < 8; ++ct) {
                    const int cc = ct*16 + la;
                    short8 a0 = *(short8*)(lds + W2T_OFF + cc*128 + (((lb  ) ^ (cc&7))<<4));
                    short8 a1 = *(short8*)(lds + W2T_OFF + cc*128 + (((lb+4) ^ (cc&7))<<4));
                    f32x4 acc = {0.f, 0.f, 0.f, 0.f};
                    acc = __builtin_amdgcn_mfma_f32_16x16x32_bf16(a0, hb0, acc, 0, 0, 0);
                    acc = __builtin_amdgcn_mfma_f32_16x16x32_bf16(a1, hb1, acc, 0, 0, 0);
                    float4 bb = *(float4*)&sB2[ct*16 + lb*4];
                    float e0 = fmaxf(acc[0] + bb.x, 0.f);
                    float e1 = fmaxf(acc[1] + bb.y, 0.f);
                    float e2 = fmaxf(acc[2] + bb.z, 0.f);
                    float e3 = fmaxf(acc[3] + bb.w, 0.f);
                    uint2 pk; pk.x = cvtpk(e0, e1); pk.y = cvtpk(e2, e3);
                    const int gg = ct*2 + (lb>>1);
                    *(uint2*)(wlds + H2S + la*256 + ((gg ^ la)<<4) + (lb&1)*8) = pk;
                }
            }

            // GEMM2: oI rows 16s+la = H2s @ W3 + AN @ Wi + bc, masked
            {
                short8 B0 = *(short8*)(wlds + H2S + la*256 + ((( 0 + lb) ^ la)<<4));
                short8 B1 = *(short8*)(wlds + H2S + la*256 + ((( 4 + lb) ^ la)<<4));
                short8 B2v= *(short8*)(wlds + H2S + la*256 + ((( 8 + lb) ^ la)<<4));
                short8 B3 = *(short8*)(wlds + H2S + la*256 + (((12 + lb) ^ la)<<4));
                const int row = 16*s + la;
                short8 bA = *(short8*)(wlds + ANB + row*64 + ((lb ^ (row&3))<<4));
                float mk = smk[row];
                float* orow = oI + (Rb + row) * 96;
                #pragma unroll
                for (int ct = 0; ct < 6; ++ct) {
                    const int cc = ct*16 + la;
                    f32x4 acc = {0.f, 0.f, 0.f, 0.f};
                    short8 A0 = *(short8*)(lds + W3T_OFF + cc*256 + ((( 0 + lb) ^ (cc&15))<<4));
                    short8 A1 = *(short8*)(lds + W3T_OFF + cc*256 + ((( 4 + lb) ^ (cc&15))<<4));
                    short8 A2 = *(short8*)(lds + W3T_OFF + cc*256 + ((( 8 + lb) ^ (cc&15))<<4));
                    short8 A3 = *(short8*)(lds + W3T_OFF + cc*256 + (((12 + lb) ^ (cc&15))<<4));
                    acc = __builtin_amdgcn_mfma_f32_16x16x32_bf16(A0, B0, acc, 0, 0, 0);
                    acc = __builtin_amdgcn_mfma_f32_16x16x32_bf16(A1, B1, acc, 0, 0, 0);
                    acc = __builtin_amdgcn_mfma_f32_16x16x32_bf16(A2, B2v, acc, 0, 0, 0);
                    acc = __builtin_amdgcn_mfma_f32_16x16x32_bf16(A3, B3, acc, 0, 0, 0);
                    short8 Aw = *(short8*)(lds + WIT_OFF + cc*64 + ((lb ^ (cc&3))<<4));
                    acc = __builtin_amdgcn_mfma_f32_16x16x32_bf16(Aw, bA, acc, 0, 0, 0);
                    float4 bb = *(float4*)&sBC[ct*16 + lb*4];
                    float4 o;
                    o.x = (mk != 0.f) ? acc[0] + bb.x : 0.f;
                    o.y = (mk != 0.f) ? acc[1] + bb.y : 0.f;
                    o.z = (mk != 0.f) ? acc[2] + bb.z : 0.f;
                    o.w = (mk != 0.f) ? acc[3] + bb.w : 0.f;
                    *(float4*)(orow + ct*16 + lb*4) = o;
                }
            }
        }

        n = nx;
    }
}

extern "C" void kernel_launch(void* const* d_in, const int* in_sizes, int n_in,
                              void* d_out, int out_size, void* d_ws, size_t ws_size,
                              hipStream_t stream)
{
    const float* gp  = (const float*)d_in[0];
    const float* zb  = (const float*)d_in[2];
    const float* w2c = (const float*)d_in[3];
    const float* ck  = (const float*)d_in[4];
    const float* vo  = (const float*)d_in[5];
    const float* ss  = (const float*)d_in[6];
    const float* cvr = (const float*)d_in[7];
    const float* Wi  = (const float*)d_in[8];
    const float* bi  = (const float*)d_in[9];
    const float* W1  = (const float*)d_in[10];
    const float* b1  = (const float*)d_in[11];
    const float* W2  = (const float*)d_in[12];
    const float* b2  = (const float*)d_in[13];
    const float* W3  = (const float*)d_in[14];
    const float* b3  = (const float*)d_in[15];

    float* out = (float*)d_out;
    const long N = NG;
    float* oA = out;               // (N,23)
    float* oT = out + 23L * N;     // (N,)
    float* oI = out + 24L * N;     // (N,96)
    float* oP = out + 120L * N;    // (N,25)
    float* oM = out + 145L * N;    // (N,)

    int usews = (ws_size >= 4) ? 1 : 0;
    int* ctr = (int*)d_ws;
    if (usews) hipMemsetAsync(d_ws, 0, 4, stream);

    k_main<<<GRID, BLK, 0, stream>>>(gp, zb, w2c, ck, vo, ss, cvr,
                                     W1, b1, W2, b2, W3, b3, Wi, bi,
                                     oA, oT, oI, oP, oM, ctr, usews);
}

// Round 14
// 174.209 us; speedup vs baseline: 1.0862x; 1.0811x over previous
//
#include <hip/hip_runtime.h>
#include <math.h>

#define NG 800000        // = 12500 chunks of 64 rows
#define NCH 12500
#define GRID 256
#define BLK 512
#define WPB 8
#define NSTATIC 2048     // GRID * WPB

typedef __attribute__((ext_vector_type(8))) short short8;
typedef __attribute__((ext_vector_type(4))) float f32x4;

// ---- shared LDS layout (bytes) ----
#define W2T_OFF 0        // 16384  [c=128][k=64] bf16 swz
#define W3T_OFF 16384    // 24576  [c=96][k=128] bf16 swz
#define WIT_OFF 40960    //  6144  [c=96][k=32]  bf16 swz
#define B2_OFF  47104    //   512  f32[128]
#define BC_OFF  47616    //   384  f32[96]
#define WV_OFF  48128    // 8 waves x 11264
// per-wave region (11264 B):
#define X_OFF 0          //  6400  gp tile -> oA staging -> (H1S,H2S) in strips
#define H1S   0          //  alias: 2048  [16][64]  bf16 swz strip
#define H2S   2048       //  alias: 4096  [16][128] bf16 swz strip
#define ANB   6400       //  4096  [64][32] bf16 swz
#define DFP   10496      //   512  float2[64]
#define SMK   11008      //   256  float[64]
#define WV_SZ 11264
#define LDS_TOT (WV_OFF + WPB * WV_SZ)   // 138240

__device__ __forceinline__ float sis(float t) {
    t = fminf(fmaxf(t, 0.01f), 0.99f);
    return logf(t / (1.0f - t));
}
__device__ __forceinline__ unsigned short f2bf(float f) {
    unsigned int u = __float_as_uint(f);
    return (unsigned short)((u + 0x7FFFu + ((u >> 16) & 1u)) >> 16);
}
__device__ __forceinline__ unsigned int cvtpk(float a, float b) {
    unsigned int r;
    asm("v_cvt_pk_bf16_f32 %0, %1, %2" : "=v"(r) : "v"(a), "v"(b));
    return r;
}

__global__ __launch_bounds__(BLK, 2) void k_main(
    const float* __restrict__ gp,
    const float* __restrict__ zbuf,
    const float* __restrict__ w2c,
    const float* __restrict__ ck,
    const float* __restrict__ vo,
    const float* __restrict__ ss,
    const float* __restrict__ cvr,
    const float* __restrict__ W1, const float* __restrict__ b1,
    const float* __restrict__ W2, const float* __restrict__ b2,
    const float* __restrict__ W3, const float* __restrict__ b3,
    const float* __restrict__ Wi, const float* __restrict__ bi,
    float* __restrict__ oA, float* __restrict__ oT,
    float* __restrict__ oI, float* __restrict__ oP, float* __restrict__ oM)
{
    __shared__ __align__(16) char lds[LDS_TOT];
    float* sB2 = (float*)(lds + B2_OFF);
    float* sBC = (float*)(lds + BC_OFF);

    const int t   = threadIdx.x;
    const int wv  = t >> 6;
    const int l   = t & 63;
    const int la  = l & 15;
    const int lb  = l >> 4;
    const int sub = l & 3;
    char* wlds = lds + WV_OFF + wv * WV_SZ;
    float*  xf  = (float*)(wlds + X_OFF);
    float2* dfp = (float2*)(wlds + DFP);
    float*  smk = (float*)(wlds + SMK);

    // ---- build shared weight images (once per block) ----
    for (int idx = t; idx < 8192; idx += BLK) {            // W2T
        int k = idx >> 7, c = idx & 127;
        *(unsigned short*)(lds + W2T_OFF + c*128 + (((k>>3) ^ (c&7))<<4) + (k&7)*2)
            = f2bf(W2[idx]);
    }
    for (int idx = t; idx < 12288; idx += BLK) {           // W3T
        int k = idx / 96, c = idx - k*96;
        *(unsigned short*)(lds + W3T_OFF + c*256 + (((k>>3) ^ (c&15))<<4) + (k&7)*2)
            = f2bf(W3[idx]);
    }
    for (int idx = t; idx < 3072; idx += BLK) {            // WIT
        int c = idx >> 5, k = idx & 31;
        float val = (k < 23) ? Wi[k*96 + c] : 0.0f;
        *(unsigned short*)(lds + WIT_OFF + c*64 + (((k>>3) ^ (c&3))<<4) + (k&7)*2)
            = f2bf(val);
    }
    if (t < 128) sB2[t] = b2[t];
    if (t < 96)  sBC[t] = b3[t] + bi[t];

    // per-lane W1/b1 column block (cols sub*16..sub*16+15) in registers
    float4 w1a[4], w1b[4], b1r[4];
    #pragma unroll
    for (int gi = 0; gi < 4; ++gi) {
        w1a[gi] = *(const float4*)&W1[sub*16 + gi*4];
        w1b[gi] = *(const float4*)&W1[64 + sub*16 + gi*4];
        b1r[gi] = *(const float4*)&b1[sub*16 + gi*4];
    }

    // uniforms
    const float R00=w2c[0],R01=w2c[1],R02=w2c[2],T0=w2c[3];
    const float R10=w2c[4],R11=w2c[5],R12=w2c[6],T1=w2c[7];
    const float R20=w2c[8],R21=w2c[9],R22=w2c[10],T2=w2c[11];
    const float k00=ck[0],k02=ck[2],k11=ck[4],k12=ck[5];
    const float n0=vo[0]+1e-3f, n1=vo[1]+1e-3f, n2=vo[2]+1e-3f;
    const float f0=vo[0]+ss[0]-1e-3f, f1=vo[1]+ss[1]-1e-3f, f2=vo[2]+ss[2]-1e-3f;
    const float cv0=cvr[0],cv1=cvr[1],cv2=cvr[2],cv3=cvr[3],cv4=cvr[4],cv5=cvr[5];
    const float i30=1.0f/(cv3-cv0), i41=1.0f/(cv4-cv1), i52=1.0f/(cv5-cv2);
    const float qtr = R00 + R11 + R22;
    const float qw = sqrtf(fmaxf(qtr + 1.0f, 1e-8f)) * 0.5f;
    const float qi4 = 0.25f / qw;
    const float qx = (R21-R12)*qi4, qy=(R02-R20)*qi4, qz=(R10-R01)*qi4;

    __syncthreads();   // weight images visible; ONLY barrier in the kernel

    // ---- initial prefetch of first chunk into registers ----
    int n = blockIdx.x * WPB + wv;
    float4 pf[7];
    {
        const int pc = (n < NCH) ? n : 0;
        const float4* g4 = (const float4*)(gp + (long)pc * 1600);
        #pragma unroll
        for (int i = 0; i < 7; ++i) {
            int k = l + i*64;
            if (k < 400) pf[i] = g4[k];
        }
    }

    // ---- per-wave free-running loop over 64-row chunks ----
    while (n < NCH) {
        const long Rb = (long)n * 64;
        const long R  = Rb + l;
        const int nx = n + NSTATIC;          // static next chunk (known early)

        // -- publish prefetched gp tile to wave-private LDS --
        {
            float4* x4 = (float4*)xf;
            #pragma unroll
            for (int i = 0; i < 7; ++i) {
                int k = l + i*64;
                if (k < 400) x4[k] = pf[i];
            }
        }

        // -- own row from LDS (conflict-free b32 reads) --
        float v[25];
        #pragma unroll
        for (int j = 0; j < 25; ++j) v[j] = xf[l*25 + j];

        // -- geometry --
        const float x=v[0], y=v[1], zz=v[2];
        const float c0 = R00*x + R01*y + R02*zz + T0;
        const float c1 = R10*x + R11*y + R12*zz + T1;
        const float c2 = R20*x + R21*y + R22*zz + T2;

        bool m1 = c2 > 1e-6f;
        float zc = m1 ? c2 : 1e-6f;
        float fpx = k00 * c0 / zc + k02;
        float fpy = k11 * c1 / zc + k12;
        bool m2 = (fpx >= 0.f) && (fpx < 640.f) && (fpy >= 0.f) && (fpy < 480.f);
        bool mall = m1 && m2;
        bool gpm = (x>n0)&&(x<f0)&&(y>n1)&&(y<f1)&&(zz>n2)&&(zz<f2);
        bool mdet = mall && gpm;
        float tag = (v[23] == 1.0f) ? 0.5f : 0.0f;
        if (!mdet) tag = 1.0f;
        bool gm = (c0>=cv0)&&(c0<=cv3)&&(c1>=cv1)&&(c1<=cv4)&&(c2>=cv2)&&(c2<=cv5);
        bool reuse = gpm && gm;

        // df gather (issued before the next-chunk prefetch loads)
        float czs = (fabsf(c2) < 1e-6f) ? 1e-6f : c2;
        float px = k00*c0/czs + k02;
        float py = k11*c1/czs + k12;
        int ix = (int)fminf(fmaxf(px, 0.f), 639.f);
        int iy = (int)fminf(fmaxf(py, 0.f), 479.f);
        float d0g = zbuf[iy*640 + ix];

        // -- ISSUE next chunk's prefetch NOW: before any store bursts, so the
        //    next-iteration publish waits only on these (in-order vmcnt) --
        {
            const int pc = (nx < NCH) ? nx : 0;
            const float4* g4 = (const float4*)(gp + (long)pc * 1600);
            #pragma unroll
            for (int i = 0; i < 7; ++i) {
                int k = l + i*64;
                if (k < 400) pf[i] = g4[k];
            }
        }

        oM[R] = reuse ? 1.0f : 0.0f;
        oT[R] = reuse ? tag : 0.0f;
        smk[l] = reuse ? 1.0f : 0.0f;
        dfp[l] = make_float2(d0g, c2);

        // -- patch col 24 in the LDS tile, then coalesced oP copy --
        xf[l*25 + 24] = gpm ? 1.0f : v[24];
        {
            float4* pd = (float4*)(oP + Rb * 25);
            const float4* x4 = (const float4*)xf;
            #pragma unroll
            for (int i = 0; i < 7; ++i) {
                int k = l + i*64;
                if (k < 400) pd[k] = x4[k];
            }
        }

        // -- anchor --
        float ar[23];
        if (reuse) {
            float p0=v[6], p1=v[7], p2=v[8], p3=v[9];
            ar[0] = sis((c0 - cv0) * i30);
            ar[1] = sis((c1 - cv1) * i41);
            ar[2] = sis((c2 - cv2) * i52);
            ar[3] = sis(v[3]); ar[4] = sis(v[4]); ar[5] = sis(v[5]);
            ar[6] = qw*p0 - qx*p1 - qy*p2 - qz*p3;
            ar[7] = qw*p1 + qx*p0 + qy*p3 - qz*p2;
            ar[8] = qw*p2 - qx*p3 + qy*p0 + qz*p1;
            ar[9] = qw*p3 + qx*p2 - qy*p1 + qz*p0;
            ar[10] = sis(v[10]);
            #pragma unroll
            for (int j = 0; j < 12; ++j) ar[11+j] = v[11+j];
        } else {
            #pragma unroll
            for (int j = 0; j < 23; ++j) ar[j] = 0.0f;
        }

        // -- anchors into LDS tile (overwrites gp tile), coalesced oA copy --
        #pragma unroll
        for (int j = 0; j < 23; ++j) xf[l*23 + j] = ar[j];
        {
            float4* ad = (float4*)(oA + Rb * 23);
            const float4* x4 = (const float4*)xf;
            #pragma unroll
            for (int i = 0; i < 6; ++i) {
                int k = l + i*64;
                if (k < 368) ad[k] = x4[k];
            }
        }

        // -- AN image: own row l, 32 cols bf16 (23 real), swizzled --
        {
            uint4 a0u, a1u, a2u, a3u;
            a0u.x=cvtpk(ar[0],ar[1]);   a0u.y=cvtpk(ar[2],ar[3]);
            a0u.z=cvtpk(ar[4],ar[5]);   a0u.w=cvtpk(ar[6],ar[7]);
            a1u.x=cvtpk(ar[8],ar[9]);   a1u.y=cvtpk(ar[10],ar[11]);
            a1u.z=cvtpk(ar[12],ar[13]); a1u.w=cvtpk(ar[14],ar[15]);
            a2u.x=cvtpk(ar[16],ar[17]); a2u.y=cvtpk(ar[18],ar[19]);
            a2u.z=cvtpk(ar[20],ar[21]); a2u.w=cvtpk(ar[22],0.0f);
            a3u.x=0u; a3u.y=0u; a3u.z=0u; a3u.w=0u;
            char* anr = wlds + ANB + l*64;
            *(uint4*)(anr + ((0 ^ (l&3))<<4)) = a0u;
            *(uint4*)(anr + ((1 ^ (l&3))<<4)) = a1u;
            *(uint4*)(anr + ((2 ^ (l&3))<<4)) = a2u;
            *(uint4*)(anr + ((3 ^ (l&3))<<4)) = a3u;
        }

        // ---- 4 strips of 16 rows: H1 -> GEMM1 -> GEMM2 ----
        for (int s = 0; s < 4; ++s) {
            // H1 strip: lane computes row (l>>2)'s cols sub*16..+15
            {
                const int rr = l >> 2;
                float2 dfv = dfp[16*s + rr];
                float h[16];
                #pragma unroll
                for (int gi = 0; gi < 4; ++gi) {
                    h[gi*4+0] = fmaxf(fmaf(dfv.x, w1a[gi].x, fmaf(dfv.y, w1b[gi].x, b1r[gi].x)), 0.f);
                    h[gi*4+1] = fmaxf(fmaf(dfv.x, w1a[gi].y, fmaf(dfv.y, w1b[gi].y, b1r[gi].y)), 0.f);
                    h[gi*4+2] = fmaxf(fmaf(dfv.x, w1a[gi].z, fmaf(dfv.y, w1b[gi].z, b1r[gi].z)), 0.f);
                    h[gi*4+3] = fmaxf(fmaf(dfv.x, w1a[gi].w, fmaf(dfv.y, w1b[gi].w, b1r[gi].w)), 0.f);
                }
                uint4 pa, pb;
                pa.x = cvtpk(h[0],h[1]);   pa.y = cvtpk(h[2],h[3]);
                pa.z = cvtpk(h[4],h[5]);   pa.w = cvtpk(h[6],h[7]);
                pb.x = cvtpk(h[8],h[9]);   pb.y = cvtpk(h[10],h[11]);
                pb.z = cvtpk(h[12],h[13]); pb.w = cvtpk(h[14],h[15]);
                char* h1r = wlds + H1S + rr*128;
                *(uint4*)(h1r + (((2*sub  ) ^ (rr&7))<<4)) = pa;
                *(uint4*)(h1r + (((2*sub+1) ^ (rr&7))<<4)) = pb;
            }

            // GEMM1: H2s[la][128] = relu(H1s[la] @ W2 + b2)
            {
                short8 hb0 = *(short8*)(wlds + H1S + la*128 + (((lb  ) ^ (la&7))<<4));
                short8 hb1 = *(short8*)(wlds + H1S + la*128 + (((lb+4) ^ (la&7))<<4));
                #pragma unroll
                for (int ct = 0; ct < 8; ++ct) {
                    const int cc = ct*16 + la;
                    short8 a0 = *(short8*)(lds + W2T_OFF + cc*128 + (((lb  ) ^ (cc&7))<<4));
                    short8 a1 = *(short8*)(lds + W2T_OFF + cc*128 + (((lb+4) ^ (cc&7))<<4));
                    f32x4 acc = {0.f, 0.f, 0.f, 0.f};
                    acc = __builtin_amdgcn_mfma_f32_16x16x32_bf16(a0, hb0, acc, 0, 0, 0);
                    acc = __builtin_amdgcn_mfma_f32_16x16x32_bf16(a1, hb1, acc, 0, 0, 0);
                    float4 bb = *(float4*)&sB2[ct*16 + lb*4];
                    float e0 = fmaxf(acc[0] + bb.x, 0.f);
                    float e1 = fmaxf(acc[1] + bb.y, 0.f);
                    float e2 = fmaxf(acc[2] + bb.z, 0.f);
                    float e3 = fmaxf(acc[3] + bb.w, 0.f);
                    uint2 pk; pk.x = cvtpk(e0, e1); pk.y = cvtpk(e2, e3);
                    const int gg = ct*2 + (lb>>1);
                    *(uint2*)(wlds + H2S + la*256 + ((gg ^ la)<<4) + (lb&1)*8) = pk;
                }
            }

            // GEMM2: oI rows 16s+la = H2s @ W3 + AN @ Wi + bc, masked
            {
                short8 B0 = *(short8*)(wlds + H2S + la*256 + ((( 0 + lb) ^ la)<<4));
                short8 B1 = *(short8*)(wlds + H2S + la*256 + ((( 4 + lb) ^ la)<<4));
                short8 B2v= *(short8*)(wlds + H2S + la*256 + ((( 8 + lb) ^ la)<<4));
                short8 B3 = *(short8*)(wlds + H2S + la*256 + (((12 + lb) ^ la)<<4));
                const int row = 16*s + la;
                short8 bA = *(short8*)(wlds + ANB + row*64 + ((lb ^ (row&3))<<4));
                float mk = smk[row];
                float* orow = oI + (Rb + row) * 96;
                #pragma unroll
                for (int ct = 0; ct < 6; ++ct) {
                    const int cc = ct*16 + la;
                    f32x4 acc = {0.f, 0.f, 0.f, 0.f};
                    short8 A0 = *(short8*)(lds + W3T_OFF + cc*256 + ((( 0 + lb) ^ (cc&15))<<4));
                    short8 A1 = *(short8*)(lds + W3T_OFF + cc*256 + ((( 4 + lb) ^ (cc&15))<<4));
                    short8 A2 = *(short8*)(lds + W3T_OFF + cc*256 + ((( 8 + lb) ^ (cc&15))<<4));
                    short8 A3 = *(short8*)(lds + W3T_OFF + cc*256 + (((12 + lb) ^ (cc&15))<<4));
                    acc = __builtin_amdgcn_mfma_f32_16x16x32_bf16(A0, B0, acc, 0, 0, 0);
                    acc = __builtin_amdgcn_mfma_f32_16x16x32_bf16(A1, B1, acc, 0, 0, 0);
                    acc = __builtin_amdgcn_mfma_f32_16x16x32_bf16(A2, B2v, acc, 0, 0, 0);
                    acc = __builtin_amdgcn_mfma_f32_16x16x32_bf16(A3, B3, acc, 0, 0, 0);
                    short8 Aw = *(short8*)(lds + WIT_OFF + cc*64 + ((lb ^ (cc&3))<<4));
                    acc = __builtin_amdgcn_mfma_f32_16x16x32_bf16(Aw, bA, acc, 0, 0, 0);
                    float4 bb = *(float4*)&sBC[ct*16 + lb*4];
                    float4 o;
                    o.x = (mk != 0.f) ? acc[0] + bb.x : 0.f;
                    o.y = (mk != 0.f) ? acc[1] + bb.y : 0.f;
                    o.z = (mk != 0.f) ? acc[2] + bb.z : 0.f;
                    o.w = (mk != 0.f) ? acc[3] + bb.w : 0.f;
                    *(float4*)(orow + ct*16 + lb*4) = o;
                }
            }
        }

        n = nx;
    }
}

extern "C" void kernel_launch(void* const* d_in, const int* in_sizes, int n_in,
                              void* d_out, int out_size, void* d_ws, size_t ws_size,
                              hipStream_t stream)
{
    const float* gp  = (const float*)d_in[0];
    const float* zb  = (const float*)d_in[2];
    const float* w2c = (const float*)d_in[3];
    const float* ck  = (const float*)d_in[4];
    const float* vo  = (const float*)d_in[5];
    const float* ss  = (const float*)d_in[6];
    const float* cvr = (const float*)d_in[7];
    const float* Wi  = (const float*)d_in[8];
    const float* bi  = (const float*)d_in[9];
    const float* W1  = (const float*)d_in[10];
    const float* b1  = (const float*)d_in[11];
    const float* W2  = (const float*)d_in[12];
    const float* b2  = (const float*)d_in[13];
    const float* W3  = (const float*)d_in[14];
    const float* b3  = (const float*)d_in[15];

    float* out = (float*)d_out;
    const long N = NG;
    float* oA = out;               // (N,23)
    float* oT = out + 23L * N;     // (N,)
    float* oI = out + 24L * N;     // (N,96)
    float* oP = out + 120L * N;    // (N,25)
    float* oM = out + 145L * N;    // (N,)

    k_main<<<GRID, BLK, 0, stream>>>(gp, zb, w2c, ck, vo, ss, cvr,
                                     W1, b1, W2, b2, W3, b3, Wi, bi,
                                     oA, oT, oI, oP, oM);
}

// Round 15
// 144.021 us; speedup vs baseline: 1.3139x; 1.2096x over previous
//
#include <hip/hip_runtime.h>
#include <math.h>

#define NG 800000        // = 12500 chunks of 64 rows
#define NCH 12500
#define GRID 256
#define BLK 512
#define WPB 8
#define NSTATIC 2048     // GRID * WPB

typedef __attribute__((ext_vector_type(8))) short short8;
typedef __attribute__((ext_vector_type(4))) float f32x4;

// ---- shared LDS layout (bytes) ----
#define W2T_OFF 0        // 16384  [c=128][k=64] bf16 swz
#define W3T_OFF 16384    // 24576  [c=96][k=128] bf16 swz
#define WIT_OFF 40960    //  4608  [c=96][k=24]  bf16 linear 48B rows
#define B2_OFF  45568    //   512  f32[128]
#define BC_OFF  46080    //   384  f32[96]
#define WV_OFF  46464    // 8 waves x 14336
// per-wave region (14336 B):
#define X_OFF 0          //  6400  gp tile -> oA staging; gload target for next chunk
#define H2S   6400       //  4096  [16][128] bf16 swz strip (separate from X!)
#define ANB   10496      //  3072  [64][24] bf16 linear 48B rows
#define DFP   13568      //   512  float2[64]
#define SMK   14080      //   256  float[64]
#define WV_SZ 14336
#define LDS_TOT (WV_OFF + WPB * WV_SZ)   // 161152 <= 163840

__device__ __forceinline__ float sis(float t) {
    t = fminf(fmaxf(t, 0.01f), 0.99f);
    return logf(t / (1.0f - t));
}
__device__ __forceinline__ unsigned short f2bf(float f) {
    unsigned int u = __float_as_uint(f);
    return (unsigned short)((u + 0x7FFFu + ((u >> 16) & 1u)) >> 16);
}
__device__ __forceinline__ unsigned int cvtpk(float a, float b) {
    unsigned int r;
    asm("v_cvt_pk_bf16_f32 %0, %1, %2" : "=v"(r) : "v"(a), "v"(b));
    return r;
}
__device__ __forceinline__ void gload16(const float* g, char* l) {
    __builtin_amdgcn_global_load_lds(
        (const __attribute__((address_space(1))) void*)g,
        (__attribute__((address_space(3))) void*)l, 16, 0, 0);
}
union S8 { uint4 q; short8 v; };

__global__ __launch_bounds__(BLK, 2) void k_main(
    const float* __restrict__ gp,
    const float* __restrict__ zbuf,
    const float* __restrict__ w2c,
    const float* __restrict__ ck,
    const float* __restrict__ vo,
    const float* __restrict__ ss,
    const float* __restrict__ cvr,
    const float* __restrict__ W1, const float* __restrict__ b1,
    const float* __restrict__ W2, const float* __restrict__ b2,
    const float* __restrict__ W3, const float* __restrict__ b3,
    const float* __restrict__ Wi, const float* __restrict__ bi,
    float* __restrict__ oA, float* __restrict__ oT,
    float* __restrict__ oI, float* __restrict__ oP, float* __restrict__ oM)
{
    __shared__ __align__(16) char lds[LDS_TOT];
    float* sB2 = (float*)(lds + B2_OFF);
    float* sBC = (float*)(lds + BC_OFF);

    const int t   = threadIdx.x;
    const int wv  = t >> 6;
    const int l   = t & 63;
    const int la  = l & 15;
    const int lb  = l >> 4;
    char* wlds = lds + WV_OFF + wv * WV_SZ;
    float*  xf  = (float*)(wlds + X_OFF);
    float2* dfp = (float2*)(wlds + DFP);
    float*  smk = (float*)(wlds + SMK);

    // ---- build shared weight images (once per block) ----
    for (int idx = t; idx < 8192; idx += BLK) {            // W2T
        int k = idx >> 7, c = idx & 127;
        *(unsigned short*)(lds + W2T_OFF + c*128 + (((k>>3) ^ (c&7))<<4) + (k&7)*2)
            = f2bf(W2[idx]);
    }
    for (int idx = t; idx < 12288; idx += BLK) {           // W3T
        int k = idx / 96, c = idx - k*96;
        *(unsigned short*)(lds + W3T_OFF + c*256 + (((k>>3) ^ (c&15))<<4) + (k&7)*2)
            = f2bf(W3[idx]);
    }
    for (int idx = t; idx < 2304; idx += BLK) {            // WIT 48B rows
        int c = idx / 24, k = idx - c*24;
        float val = (k < 23) ? Wi[k*96 + c] : 0.0f;
        *(unsigned short*)(lds + WIT_OFF + c*48 + k*2) = f2bf(val);
    }
    if (t < 128) sB2[t] = b2[t];
    if (t < 96)  sBC[t] = b3[t] + bi[t];

    // per-lane W1/b1 for this lane's B-fragment k-columns:
    // k = lb*8+j (first set) and 32+lb*8+j (second set)
    const int kb = lb * 8;
    float w1x[16], w1y[16], w1z[16];
    #pragma unroll
    for (int j = 0; j < 8; ++j) {
        w1x[j]   = W1[kb + j];       w1y[j]   = W1[64 + kb + j];   w1z[j]   = b1[kb + j];
        w1x[8+j] = W1[32 + kb + j];  w1y[8+j] = W1[96 + kb + j];   w1z[8+j] = b1[32 + kb + j];
    }

    // uniforms
    const float R00=w2c[0],R01=w2c[1],R02=w2c[2],T0=w2c[3];
    const float R10=w2c[4],R11=w2c[5],R12=w2c[6],T1=w2c[7];
    const float R20=w2c[8],R21=w2c[9],R22=w2c[10],T2=w2c[11];
    const float k00=ck[0],k02=ck[2],k11=ck[4],k12=ck[5];
    const float n0=vo[0]+1e-3f, n1=vo[1]+1e-3f, n2=vo[2]+1e-3f;
    const float f0=vo[0]+ss[0]-1e-3f, f1=vo[1]+ss[1]-1e-3f, f2=vo[2]+ss[2]-1e-3f;
    const float cv0=cvr[0],cv1=cvr[1],cv2=cvr[2],cv3=cvr[3],cv4=cvr[4],cv5=cvr[5];
    const float i30=1.0f/(cv3-cv0), i41=1.0f/(cv4-cv1), i52=1.0f/(cv5-cv2);
    const float qtr = R00 + R11 + R22;
    const float qw = sqrtf(fmaxf(qtr + 1.0f, 1e-8f)) * 0.5f;
    const float qi4 = 0.25f / qw;
    const float qx = (R21-R12)*qi4, qy=(R02-R20)*qi4, qz=(R10-R01)*qi4;

    __syncthreads();   // weight images visible; ONLY barrier in the kernel

    // ---- prologue: stage first chunk into X via global_load_lds, drain ----
    int n = blockIdx.x * WPB + wv;
    {
        const int pc = (n < NCH) ? n : 0;
        const float* base = gp + (long)pc * 1600;
        #pragma unroll
        for (int i = 0; i < 6; ++i)
            gload16(base + (l + i*64)*4, wlds + X_OFF + i*1024);
        if (l < 16)
            gload16(base + (l + 384)*4, wlds + X_OFF + 6144);
        asm volatile("s_waitcnt vmcnt(0)" ::: "memory");
    }

    // ---- per-wave free-running loop over 64-row chunks ----
    while (n < NCH) {
        // gloads for this chunk were issued last iteration, followed by the
        // 24 oI stores; in-order vmcnt retirement => vmcnt(24) <=> gloads done
        asm volatile("s_waitcnt vmcnt(24)" ::: "memory");

        const long Rb = (long)n * 64;
        const long R  = Rb + l;
        const int nx = n + NSTATIC;

        // -- own row from LDS (conflict-free b32 reads) --
        float v[25];
        #pragma unroll
        for (int j = 0; j < 25; ++j) v[j] = xf[l*25 + j];

        // -- geometry --
        const float x=v[0], y=v[1], zz=v[2];
        const float c0 = R00*x + R01*y + R02*zz + T0;
        const float c1 = R10*x + R11*y + R12*zz + T1;
        const float c2 = R20*x + R21*y + R22*zz + T2;

        bool m1 = c2 > 1e-6f;
        float zc = m1 ? c2 : 1e-6f;
        float fpx = k00 * c0 / zc + k02;
        float fpy = k11 * c1 / zc + k12;
        bool m2 = (fpx >= 0.f) && (fpx < 640.f) && (fpy >= 0.f) && (fpy < 480.f);
        bool mall = m1 && m2;
        bool gpm = (x>n0)&&(x<f0)&&(y>n1)&&(y<f1)&&(zz>n2)&&(zz<f2);
        bool mdet = mall && gpm;
        float tag = (v[23] == 1.0f) ? 0.5f : 0.0f;
        if (!mdet) tag = 1.0f;
        bool gm = (c0>=cv0)&&(c0<=cv3)&&(c1>=cv1)&&(c1<=cv4)&&(c2>=cv2)&&(c2<=cv5);
        bool reuse = gpm && gm;

        oM[R] = reuse ? 1.0f : 0.0f;
        oT[R] = reuse ? tag : 0.0f;
        smk[l] = reuse ? 1.0f : 0.0f;

        // df (fp32)
        float czs = (fabsf(c2) < 1e-6f) ? 1e-6f : c2;
        float px = k00*c0/czs + k02;
        float py = k11*c1/czs + k12;
        int ix = (int)fminf(fmaxf(px, 0.f), 639.f);
        int iy = (int)fminf(fmaxf(py, 0.f), 479.f);
        float d0g = zbuf[iy*640 + ix];
        dfp[l] = make_float2(d0g, c2);

        // -- patch col 24 in the LDS tile, then coalesced oP copy --
        xf[l*25 + 24] = gpm ? 1.0f : v[24];
        {
            float4* pd = (float4*)(oP + Rb * 25);
            const float4* x4 = (const float4*)xf;
            #pragma unroll
            for (int i = 0; i < 7; ++i) {
                int k = l + i*64;
                if (k < 400) pd[k] = x4[k];
            }
        }

        // -- anchor --
        float ar[23];
        if (reuse) {
            float p0=v[6], p1=v[7], p2=v[8], p3=v[9];
            ar[0] = sis((c0 - cv0) * i30);
            ar[1] = sis((c1 - cv1) * i41);
            ar[2] = sis((c2 - cv2) * i52);
            ar[3] = sis(v[3]); ar[4] = sis(v[4]); ar[5] = sis(v[5]);
            ar[6] = qw*p0 - qx*p1 - qy*p2 - qz*p3;
            ar[7] = qw*p1 + qx*p0 + qy*p3 - qz*p2;
            ar[8] = qw*p2 - qx*p3 + qy*p0 + qz*p1;
            ar[9] = qw*p3 + qx*p2 - qy*p1 + qz*p0;
            ar[10] = sis(v[10]);
            #pragma unroll
            for (int j = 0; j < 12; ++j) ar[11+j] = v[11+j];
        } else {
            #pragma unroll
            for (int j = 0; j < 23; ++j) ar[j] = 0.0f;
        }

        // -- anchors into X (overwrites gp tile), coalesced oA copy --
        #pragma unroll
        for (int j = 0; j < 23; ++j) xf[l*23 + j] = ar[j];
        {
            float4* ad = (float4*)(oA + Rb * 23);
            const float4* x4 = (const float4*)xf;
            #pragma unroll
            for (int i = 0; i < 6; ++i) {
                int k = l + i*64;
                if (k < 368) ad[k] = x4[k];
            }
        }

        // -- AN image: own row l, 24 bf16 (k=23 zero), 48B rows --
        {
            char* anr = wlds + ANB + l*48;
            uint4 u0, u1, u2;
            u0.x=cvtpk(ar[0],ar[1]);   u0.y=cvtpk(ar[2],ar[3]);
            u0.z=cvtpk(ar[4],ar[5]);   u0.w=cvtpk(ar[6],ar[7]);
            u1.x=cvtpk(ar[8],ar[9]);   u1.y=cvtpk(ar[10],ar[11]);
            u1.z=cvtpk(ar[12],ar[13]); u1.w=cvtpk(ar[14],ar[15]);
            u2.x=cvtpk(ar[16],ar[17]); u2.y=cvtpk(ar[18],ar[19]);
            u2.z=cvtpk(ar[20],ar[21]); u2.w=cvtpk(ar[22],0.0f);
            *(uint4*)(anr)      = u0;
            *(uint4*)(anr + 16) = u1;
            *(uint4*)(anr + 32) = u2;
        }

        // -- X is free: issue next chunk's gloads (DMA, no VGPRs).
        //    They drain under the strips; oI stores below are younger.
        if (nx < NCH) {
            const float* base = gp + (long)nx * 1600;
            #pragma unroll
            for (int i = 0; i < 6; ++i)
                gload16(base + (l + i*64)*4, wlds + X_OFF + i*1024);
            if (l < 16)
                gload16(base + (l + 384)*4, wlds + X_OFF + 6144);
        }

        // ---- 4 strips of 16 rows: in-lane H1 -> GEMM1 -> GEMM2 ----
        for (int s = 0; s < 4; ++s) {
            const int rsrc = 16*s + la;
            float2 dfv = dfp[rsrc];
            float mk = smk[rsrc];

            // in-lane H1 B-fragments (k = kb..kb+7 and 32+kb..32+kb+7)
            S8 hb0, hb1;
            {
                float h[16];
                #pragma unroll
                for (int j = 0; j < 16; ++j)
                    h[j] = fmaxf(fmaf(dfv.x, w1x[j], fmaf(dfv.y, w1y[j], w1z[j])), 0.f);
                hb0.q.x = cvtpk(h[0],h[1]);   hb0.q.y = cvtpk(h[2],h[3]);
                hb0.q.z = cvtpk(h[4],h[5]);   hb0.q.w = cvtpk(h[6],h[7]);
                hb1.q.x = cvtpk(h[8],h[9]);   hb1.q.y = cvtpk(h[10],h[11]);
                hb1.q.z = cvtpk(h[12],h[13]); hb1.q.w = cvtpk(h[14],h[15]);
            }

            // GEMM1: H2s[la][128] = relu(H1s[la] @ W2 + b2)
            {
                #pragma unroll
                for (int ct = 0; ct < 8; ++ct) {
                    const int cc = ct*16 + la;
                    short8 a0 = *(short8*)(lds + W2T_OFF + cc*128 + (((lb  ) ^ (cc&7))<<4));
                    short8 a1 = *(short8*)(lds + W2T_OFF + cc*128 + (((lb+4) ^ (cc&7))<<4));
                    f32x4 acc = {0.f, 0.f, 0.f, 0.f};
                    acc = __builtin_amdgcn_mfma_f32_16x16x32_bf16(a0, hb0.v, acc, 0, 0, 0);
                    acc = __builtin_amdgcn_mfma_f32_16x16x32_bf16(a1, hb1.v, acc, 0, 0, 0);
                    float4 bb = *(float4*)&sB2[ct*16 + lb*4];
                    float e0 = fmaxf(acc[0] + bb.x, 0.f);
                    float e1 = fmaxf(acc[1] + bb.y, 0.f);
                    float e2 = fmaxf(acc[2] + bb.z, 0.f);
                    float e3 = fmaxf(acc[3] + bb.w, 0.f);
                    uint2 pk; pk.x = cvtpk(e0, e1); pk.y = cvtpk(e2, e3);
                    const int gg = ct*2 + (lb>>1);
                    *(uint2*)(wlds + H2S + la*256 + ((gg ^ la)<<4) + (lb&1)*8) = pk;
                }
            }

            // GEMM2: oI rows 16s+la = H2s @ W3 + AN @ Wi + bc, masked
            {
                short8 B0 = *(short8*)(wlds + H2S + la*256 + ((( 0 + lb) ^ la)<<4));
                short8 B1 = *(short8*)(wlds + H2S + la*256 + ((( 4 + lb) ^ la)<<4));
                short8 B2v= *(short8*)(wlds + H2S + la*256 + ((( 8 + lb) ^ la)<<4));
                short8 B3 = *(short8*)(wlds + H2S + la*256 + (((12 + lb) ^ la)<<4));
                short8 bA;
                if (lb < 3) bA = *(short8*)(wlds + ANB + rsrc*48 + lb*16);
                else { S8 z; z.q = make_uint4(0,0,0,0); bA = z.v; }
                float* orow = oI + (Rb + rsrc) * 96;
                #pragma unroll
                for (int ct = 0; ct < 6; ++ct) {
                    const int cc = ct*16 + la;
                    f32x4 acc = {0.f, 0.f, 0.f, 0.f};
                    short8 A0 = *(short8*)(lds + W3T_OFF + cc*256 + ((( 0 + lb) ^ (cc&15))<<4));
                    short8 A1 = *(short8*)(lds + W3T_OFF + cc*256 + ((( 4 + lb) ^ (cc&15))<<4));
                    short8 A2 = *(short8*)(lds + W3T_OFF + cc*256 + ((( 8 + lb) ^ (cc&15))<<4));
                    short8 A3 = *(short8*)(lds + W3T_OFF + cc*256 + (((12 + lb) ^ (cc&15))<<4));
                    acc = __builtin_amdgcn_mfma_f32_16x16x32_bf16(A0, B0, acc, 0, 0, 0);
                    acc = __builtin_amdgcn_mfma_f32_16x16x32_bf16(A1, B1, acc, 0, 0, 0);
                    acc = __builtin_amdgcn_mfma_f32_16x16x32_bf16(A2, B2v, acc, 0, 0, 0);
                    acc = __builtin_amdgcn_mfma_f32_16x16x32_bf16(A3, B3, acc, 0, 0, 0);
                    short8 Aw;
                    if (lb < 3) Aw = *(short8*)(lds + WIT_OFF + cc*48 + lb*16);
                    else { S8 z; z.q = make_uint4(0,0,0,0); Aw = z.v; }
                    acc = __builtin_amdgcn_mfma_f32_16x16x32_bf16(Aw, bA, acc, 0, 0, 0);
                    float4 bb = *(float4*)&sBC[ct*16 + lb*4];
                    float4 o;
                    o.x = (mk != 0.f) ? acc[0] + bb.x : 0.f;
                    o.y = (mk != 0.f) ? acc[1] + bb.y : 0.f;
                    o.z = (mk != 0.f) ? acc[2] + bb.z : 0.f;
                    o.w = (mk != 0.f) ? acc[3] + bb.w : 0.f;
                    *(float4*)(orow + ct*16 + lb*4) = o;
                }
            }
        }

        n = nx;
    }
}

extern "C" void kernel_launch(void* const* d_in, const int* in_sizes, int n_in,
                              void* d_out, int out_size, void* d_ws, size_t ws_size,
                              hipStream_t stream)
{
    const float* gp  = (const float*)d_in[0];
    const float* zb  = (const float*)d_in[2];
    const float* w2c = (const float*)d_in[3];
    const float* ck  = (const float*)d_in[4];
    const float* vo  = (const float*)d_in[5];
    const float* ss  = (const float*)d_in[6];
    const float* cvr = (const float*)d_in[7];
    const float* Wi  = (const float*)d_in[8];
    const float* bi  = (const float*)d_in[9];
    const float* W1  = (const float*)d_in[10];
    const float* b1  = (const float*)d_in[11];
    const float* W2  = (const float*)d_in[12];
    const float* b2  = (const float*)d_in[13];
    const float* W3  = (const float*)d_in[14];
    const float* b3  = (const float*)d_in[15];

    float* out = (float*)d_out;
    const long N = NG;
    float* oA = out;               // (N,23)
    float* oT = out + 23L * N;     // (N,)
    float* oI = out + 24L * N;     // (N,96)
    float* oP = out + 120L * N;    // (N,25)
    float* oM = out + 145L * N;    // (N,)

    k_main<<<GRID, BLK, 0, stream>>>(gp, zb, w2c, ck, vo, ss, cvr,
                                     W1, b1, W2, b2, W3, b3, Wi, bi,
                                     oA, oT, oI, oP, oM);
}

// Round 18
// 142.299 us; speedup vs baseline: 1.3298x; 1.0121x over previous
//
#include <hip/hip_runtime.h>
#include <math.h>

#define NG 800000        // = 12500 chunks of 64 rows
#define NCH 12500
#define GRID 256
#define BLK 512
#define WPB 8
#define NSTATIC 2048     // GRID * WPB

typedef __attribute__((ext_vector_type(8))) short short8;
typedef __attribute__((ext_vector_type(4))) float f32x4;

// ---- shared LDS layout (bytes) ----
#define W2T_OFF 0        // 16384  [c=128][k=64] bf16 swz
#define W3T_OFF 16384    // 24576  [c=96][k=128] bf16 swz
#define WIT_OFF 40960    //  4608  [c=96][k=24]  bf16 linear 48B rows
#define B2_OFF  45568    //   512  f32[128]
#define BC_OFF  46080    //   384  f32[96]
#define WV_OFF  46464    // 8 waves x 14336
// per-wave region (14336 B):
#define X_OFF 0          //  6400  gp tile -> oA staging; gload target for next chunk
#define H2S   6400       //  4096  [16][128] bf16 swz strip
#define ANB   10496      //  3072  [64][24] bf16 linear 48B rows
#define DFP   13568      //   512  float2[64]
#define SMK   14080      //   256  float[64]
#define WV_SZ 14336
#define LDS_TOT (WV_OFF + WPB * WV_SZ)   // 161152 <= 163840

__device__ __forceinline__ float sis(float t) {
    t = fminf(fmaxf(t, 0.01f), 0.99f);
    return logf(t / (1.0f - t));
}
__device__ __forceinline__ unsigned short f2bf(float f) {
    unsigned int u = __float_as_uint(f);
    return (unsigned short)((u + 0x7FFFu + ((u >> 16) & 1u)) >> 16);
}
__device__ __forceinline__ unsigned int cvtpk(float a, float b) {
    unsigned int r;
    asm("v_cvt_pk_bf16_f32 %0, %1, %2" : "=v"(r) : "v"(a), "v"(b));
    return r;
}
__device__ __forceinline__ void gload16(const float* g, char* l) {
    __builtin_amdgcn_global_load_lds(
        (const __attribute__((address_space(1))) void*)g,
        (__attribute__((address_space(3))) void*)l, 16, 0, 0);
}
union S8 { uint4 q; short8 v; };

__global__ __launch_bounds__(BLK, 2) void k_main(
    const float* __restrict__ gp,
    const float* __restrict__ zbuf,
    const float* __restrict__ w2c,
    const float* __restrict__ ck,
    const float* __restrict__ vo,
    const float* __restrict__ ss,
    const float* __restrict__ cvr,
    const float* __restrict__ W1, const float* __restrict__ b1,
    const float* __restrict__ W2, const float* __restrict__ b2,
    const float* __restrict__ W3, const float* __restrict__ b3,
    const float* __restrict__ Wi, const float* __restrict__ bi,
    float* __restrict__ oA, float* __restrict__ oT,
    float* __restrict__ oI, float* __restrict__ oP, float* __restrict__ oM)
{
    __shared__ __align__(16) char lds[LDS_TOT];
    float* sB2 = (float*)(lds + B2_OFF);
    float* sBC = (float*)(lds + BC_OFF);

    const int t   = threadIdx.x;
    const int wv  = t >> 6;
    const int l   = t & 63;
    const int la  = l & 15;
    const int lb  = l >> 4;
    char* wlds = lds + WV_OFF + wv * WV_SZ;
    float*  xf  = (float*)(wlds + X_OFF);
    float2* dfp = (float2*)(wlds + DFP);
    float*  smk = (float*)(wlds + SMK);

    // ---- build shared weight images (once per block) ----
    for (int idx = t; idx < 8192; idx += BLK) {            // W2T
        int k = idx >> 7, c = idx & 127;
        *(unsigned short*)(lds + W2T_OFF + c*128 + (((k>>3) ^ (c&7))<<4) + (k&7)*2)
            = f2bf(W2[idx]);
    }
    for (int idx = t; idx < 12288; idx += BLK) {           // W3T
        int k = idx / 96, c = idx - k*96;
        *(unsigned short*)(lds + W3T_OFF + c*256 + (((k>>3) ^ (c&15))<<4) + (k&7)*2)
            = f2bf(W3[idx]);
    }
    for (int idx = t; idx < 2304; idx += BLK) {            // WIT 48B rows
        int c = idx / 24, k = idx - c*24;
        float val = (k < 23) ? Wi[k*96 + c] : 0.0f;
        *(unsigned short*)(lds + WIT_OFF + c*48 + k*2) = f2bf(val);
    }
    if (t < 128) sB2[t] = b2[t];
    if (t < 96)  sBC[t] = b3[t] + bi[t];

    // per-lane W1/b1 for this lane's B-fragment k-columns:
    // k = lb*8+j (first set) and 32+lb*8+j (second set)
    const int kb = lb * 8;
    float w1x[16], w1y[16], w1z[16];
    #pragma unroll
    for (int j = 0; j < 8; ++j) {
        w1x[j]   = W1[kb + j];       w1y[j]   = W1[64 + kb + j];   w1z[j]   = b1[kb + j];
        w1x[8+j] = W1[32 + kb + j];  w1y[8+j] = W1[96 + kb + j];   w1z[8+j] = b1[32 + kb + j];
    }

    // uniforms
    const float R00=w2c[0],R01=w2c[1],R02=w2c[2],T0=w2c[3];
    const float R10=w2c[4],R11=w2c[5],R12=w2c[6],T1=w2c[7];
    const float R20=w2c[8],R21=w2c[9],R22=w2c[10],T2=w2c[11];
    const float k00=ck[0],k02=ck[2],k11=ck[4],k12=ck[5];
    const float n0=vo[0]+1e-3f, n1=vo[1]+1e-3f, n2=vo[2]+1e-3f;
    const float f0=vo[0]+ss[0]-1e-3f, f1=vo[1]+ss[1]-1e-3f, f2=vo[2]+ss[2]-1e-3f;
    const float cv0=cvr[0],cv1=cvr[1],cv2=cvr[2],cv3=cvr[3],cv4=cvr[4],cv5=cvr[5];
    const float i30=1.0f/(cv3-cv0), i41=1.0f/(cv4-cv1), i52=1.0f/(cv5-cv2);
    const float qtr = R00 + R11 + R22;
    const float qw = sqrtf(fmaxf(qtr + 1.0f, 1e-8f)) * 0.5f;
    const float qi4 = 0.25f / qw;
    const float qx = (R21-R12)*qi4, qy=(R02-R20)*qi4, qz=(R10-R01)*qi4;

    __syncthreads();   // weight images visible; ONLY barrier in the kernel

    // ---- prologue: stage first chunk into X via global_load_lds, drain ----
    int n = blockIdx.x * WPB + wv;
    {
        const int pc = (n < NCH) ? n : 0;
        const float* base = gp + (long)pc * 1600;
        #pragma unroll
        for (int i = 0; i < 6; ++i)
            gload16(base + (l + i*64)*4, wlds + X_OFF + i*1024);
        if (l < 16)
            gload16(base + (l + 384)*4, wlds + X_OFF + 6144);
        asm volatile("s_waitcnt vmcnt(0)" ::: "memory");
    }

    // ---- per-wave free-running loop over 64-row chunks ----
    while (n < NCH) {
        // gloads for this chunk were issued last iteration, followed by the
        // 24 oI stores; in-order vmcnt retirement => vmcnt(24) <=> gloads done
        asm volatile("s_waitcnt vmcnt(24)" ::: "memory");

        const long Rb = (long)n * 64;
        const long R  = Rb + l;
        const int nx = n + NSTATIC;

        // -- own row from LDS (conflict-free b32 reads) --
        float v[25];
        #pragma unroll
        for (int j = 0; j < 25; ++j) v[j] = xf[l*25 + j];

        // -- geometry --
        const float x=v[0], y=v[1], zz=v[2];
        const float c0 = R00*x + R01*y + R02*zz + T0;
        const float c1 = R10*x + R11*y + R12*zz + T1;
        const float c2 = R20*x + R21*y + R22*zz + T2;

        bool m1 = c2 > 1e-6f;
        float zc = m1 ? c2 : 1e-6f;
        float fpx = k00 * c0 / zc + k02;
        float fpy = k11 * c1 / zc + k12;
        bool m2 = (fpx >= 0.f) && (fpx < 640.f) && (fpy >= 0.f) && (fpy < 480.f);
        bool mall = m1 && m2;
        bool gpm = (x>n0)&&(x<f0)&&(y>n1)&&(y<f1)&&(zz>n2)&&(zz<f2);
        bool mdet = mall && gpm;
        float tag = (v[23] == 1.0f) ? 0.5f : 0.0f;
        if (!mdet) tag = 1.0f;
        bool gm = (c0>=cv0)&&(c0<=cv3)&&(c1>=cv1)&&(c1<=cv4)&&(c2>=cv2)&&(c2<=cv5);
        bool reuse = gpm && gm;

        oM[R] = reuse ? 1.0f : 0.0f;
        oT[R] = reuse ? tag : 0.0f;
        smk[l] = reuse ? 1.0f : 0.0f;

        // df (fp32)
        float czs = (fabsf(c2) < 1e-6f) ? 1e-6f : c2;
        float px = k00*c0/czs + k02;
        float py = k11*c1/czs + k12;
        int ix = (int)fminf(fmaxf(px, 0.f), 639.f);
        int iy = (int)fminf(fmaxf(py, 0.f), 479.f);
        float d0g = zbuf[iy*640 + ix];
        dfp[l] = make_float2(d0g, c2);

        // -- patch col 24 in the LDS tile, then coalesced oP copy --
        xf[l*25 + 24] = gpm ? 1.0f : v[24];
        {
            float4* pd = (float4*)(oP + Rb * 25);
            const float4* x4 = (const float4*)xf;
            #pragma unroll
            for (int i = 0; i < 7; ++i) {
                int k = l + i*64;
                if (k < 400) pd[k] = x4[k];
            }
        }

        // -- anchor --
        float ar[23];
        if (reuse) {
            float p0=v[6], p1=v[7], p2=v[8], p3=v[9];
            ar[0] = sis((c0 - cv0) * i30);
            ar[1] = sis((c1 - cv1) * i41);
            ar[2] = sis((c2 - cv2) * i52);
            ar[3] = sis(v[3]); ar[4] = sis(v[4]); ar[5] = sis(v[5]);
            ar[6] = qw*p0 - qx*p1 - qy*p2 - qz*p3;
            ar[7] = qw*p1 + qx*p0 + qy*p3 - qz*p2;
            ar[8] = qw*p2 - qx*p3 + qy*p0 + qz*p1;
            ar[9] = qw*p3 + qx*p2 - qy*p1 + qz*p0;
            ar[10] = sis(v[10]);
            #pragma unroll
            for (int j = 0; j < 12; ++j) ar[11+j] = v[11+j];
        } else {
            #pragma unroll
            for (int j = 0; j < 23; ++j) ar[j] = 0.0f;
        }

        // -- anchors into X (overwrites gp tile), coalesced oA copy --
        #pragma unroll
        for (int j = 0; j < 23; ++j) xf[l*23 + j] = ar[j];
        {
            float4* ad = (float4*)(oA + Rb * 23);
            const float4* x4 = (const float4*)xf;
            #pragma unroll
            for (int i = 0; i < 6; ++i) {
                int k = l + i*64;
                if (k < 368) ad[k] = x4[k];
            }
        }

        // -- AN image: own row l, 24 bf16 (k=23 zero), 48B rows --
        {
            char* anr = wlds + ANB + l*48;
            uint4 u0, u1, u2;
            u0.x=cvtpk(ar[0],ar[1]);   u0.y=cvtpk(ar[2],ar[3]);
            u0.z=cvtpk(ar[4],ar[5]);   u0.w=cvtpk(ar[6],ar[7]);
            u1.x=cvtpk(ar[8],ar[9]);   u1.y=cvtpk(ar[10],ar[11]);
            u1.z=cvtpk(ar[12],ar[13]); u1.w=cvtpk(ar[14],ar[15]);
            u2.x=cvtpk(ar[16],ar[17]); u2.y=cvtpk(ar[18],ar[19]);
            u2.z=cvtpk(ar[20],ar[21]); u2.w=cvtpk(ar[22],0.0f);
            *(uint4*)(anr)      = u0;
            *(uint4*)(anr + 16) = u1;
            *(uint4*)(anr + 32) = u2;
        }

        // -- X is free: issue next chunk's gloads (DMA, no VGPRs).
        //    They drain under the strips; oI stores below are younger.
        if (nx < NCH) {
            const float* base = gp + (long)nx * 1600;
            #pragma unroll
            for (int i = 0; i < 6; ++i)
                gload16(base + (l + i*64)*4, wlds + X_OFF + i*1024);
            if (l < 16)
                gload16(base + (l + 384)*4, wlds + X_OFF + 6144);
        }

        // ---- 4 strips of 16 rows: in-lane H1 -> GEMM1 -> GEMM2 ----
        for (int s = 0; s < 4; ++s) {
            const int rsrc = 16*s + la;
            float2 dfv = dfp[rsrc];
            float mk = smk[rsrc];

            // in-lane H1 B-fragments (k = kb..kb+7 and 32+kb..32+kb+7)
            S8 hb0, hb1;
            {
                float h[16];
                #pragma unroll
                for (int j = 0; j < 16; ++j)
                    h[j] = fmaxf(fmaf(dfv.x, w1x[j], fmaf(dfv.y, w1y[j], w1z[j])), 0.f);
                hb0.q.x = cvtpk(h[0],h[1]);   hb0.q.y = cvtpk(h[2],h[3]);
                hb0.q.z = cvtpk(h[4],h[5]);   hb0.q.w = cvtpk(h[6],h[7]);
                hb1.q.x = cvtpk(h[8],h[9]);   hb1.q.y = cvtpk(h[10],h[11]);
                hb1.q.z = cvtpk(h[12],h[13]); hb1.q.w = cvtpk(h[14],h[15]);
            }

            // GEMM1: H2s[la][128] = relu(H1s[la] @ W2 + b2)
            {
                #pragma unroll
                for (int ct = 0; ct < 8; ++ct) {
                    const int cc = ct*16 + la;
                    short8 a0 = *(short8*)(lds + W2T_OFF + cc*128 + (((lb  ) ^ (cc&7))<<4));
                    short8 a1 = *(short8*)(lds + W2T_OFF + cc*128 + (((lb+4) ^ (cc&7))<<4));
                    f32x4 acc = {0.f, 0.f, 0.f, 0.f};
                    acc = __builtin_amdgcn_mfma_f32_16x16x32_bf16(a0, hb0.v, acc, 0, 0, 0);
                    acc = __builtin_amdgcn_mfma_f32_16x16x32_bf16(a1, hb1.v, acc, 0, 0, 0);
                    float4 bb = *(float4*)&sB2[ct*16 + lb*4];
                    float e0 = fmaxf(acc[0] + bb.x, 0.f);
                    float e1 = fmaxf(acc[1] + bb.y, 0.f);
                    float e2 = fmaxf(acc[2] + bb.z, 0.f);
                    float e3 = fmaxf(acc[3] + bb.w, 0.f);
                    uint2 pk; pk.x = cvtpk(e0, e1); pk.y = cvtpk(e2, e3);
                    const int gg = ct*2 + (lb>>1);
                    *(uint2*)(wlds + H2S + la*256 + ((gg ^ la)<<4) + (lb&1)*8) = pk;
                }
            }

            // GEMM2: oI rows 16s+la = H2s @ W3 + AN @ Wi + bc, masked
            {
                short8 B0 = *(short8*)(wlds + H2S + la*256 + ((( 0 + lb) ^ la)<<4));
                short8 B1 = *(short8*)(wlds + H2S + la*256 + ((( 4 + lb) ^ la)<<4));
                short8 B2v= *(short8*)(wlds + H2S + la*256 + ((( 8 + lb) ^ la)<<4));
                short8 B3 = *(short8*)(wlds + H2S + la*256 + (((12 + lb) ^ la)<<4));
                short8 bA;
                if (lb < 3) bA = *(short8*)(wlds + ANB + rsrc*48 + lb*16);
                else { S8 z; z.q = make_uint4(0,0,0,0); bA = z.v; }
                float* orow = oI + (Rb + rsrc) * 96;
                #pragma unroll
                for (int ct = 0; ct < 6; ++ct) {
                    const int cc = ct*16 + la;
                    f32x4 acc = {0.f, 0.f, 0.f, 0.f};
                    short8 A0 = *(short8*)(lds + W3T_OFF + cc*256 + ((( 0 + lb) ^ (cc&15))<<4));
                    short8 A1 = *(short8*)(lds + W3T_OFF + cc*256 + ((( 4 + lb) ^ (cc&15))<<4));
                    short8 A2 = *(short8*)(lds + W3T_OFF + cc*256 + ((( 8 + lb) ^ (cc&15))<<4));
                    short8 A3 = *(short8*)(lds + W3T_OFF + cc*256 + (((12 + lb) ^ (cc&15))<<4));
                    acc = __builtin_amdgcn_mfma_f32_16x16x32_bf16(A0, B0, acc, 0, 0, 0);
                    acc = __builtin_amdgcn_mfma_f32_16x16x32_bf16(A1, B1, acc, 0, 0, 0);
                    acc = __builtin_amdgcn_mfma_f32_16x16x32_bf16(A2, B2v, acc, 0, 0, 0);
                    acc = __builtin_amdgcn_mfma_f32_16x16x32_bf16(A3, B3, acc, 0, 0, 0);
                    short8 Aw;
                    if (lb < 3) Aw = *(short8*)(lds + WIT_OFF + cc*48 + lb*16);
                    else { S8 z; z.q = make_uint4(0,0,0,0); Aw = z.v; }
                    acc = __builtin_amdgcn_mfma_f32_16x16x32_bf16(Aw, bA, acc, 0, 0, 0);
                    float4 bb = *(float4*)&sBC[ct*16 + lb*4];
                    float4 o;
                    o.x = (mk != 0.f) ? acc[0] + bb.x : 0.f;
                    o.y = (mk != 0.f) ? acc[1] + bb.y : 0.f;
                    o.z = (mk != 0.f) ? acc[2] + bb.z : 0.f;
                    o.w = (mk != 0.f) ? acc[3] + bb.w : 0.f;
                    *(float4*)(orow + ct*16 + lb*4) = o;
                }
            }
        }

        n = nx;
    }
}

extern "C" void kernel_launch(void* const* d_in, const int* in_sizes, int n_in,
                              void* d_out, int out_size, void* d_ws, size_t ws_size,
                              hipStream_t stream)
{
    const float* gp  = (const float*)d_in[0];
    const float* zb  = (const float*)d_in[2];
    const float* w2c = (const float*)d_in[3];
    const float* ck  = (const float*)d_in[4];
    const float* vo  = (const float*)d_in[5];
    const float* ss  = (const float*)d_in[6];
    const float* cvr = (const float*)d_in[7];
    const float* Wi  = (const float*)d_in[8];
    const float* bi  = (const float*)d_in[9];
    const float* W1  = (const float*)d_in[10];
    const float* b1  = (const float*)d_in[11];
    const float* W2  = (const float*)d_in[12];
    const float* b2  = (const float*)d_in[13];
    const float* W3  = (const float*)d_in[14];
    const float* b3  = (const float*)d_in[15];

    float* out = (float*)d_out;
    const long N = NG;
    float* oA = out;               // (N,23)
    float* oT = out + 23L * N;     // (N,)
    float* oI = out + 24L * N;     // (N,96)
    float* oP = out + 120L * N;    // (N,25)
    float* oM = out + 145L * N;    // (N,)

    k_main<<<GRID, BLK, 0, stream>>>(gp, zb, w2c, ck, vo, ss, cvr,
                                     W1, b1, W2, b2, W3, b3, Wi, bi,
                                     oA, oT, oI, oP, oM);
}